// Round 1
// baseline (728.357 us; speedup 1.0000x reference)
//
#include <hip/hip_runtime.h>
#include <hip/hip_bf16.h>

#define N_NODES 20000
#define N_EDG   320000
#define ET      (N_EDG + N_NODES)   // edges + self loops = 340000
#define NFE     256                 // input feats
#define HD      512                 // HEADS*DIM_H
#define NH      8
#define DH      64
#define NC      16

__device__ __forceinline__ float lrelu(float v) { return v > 0.f ? v : 0.2f * v; }

// ---------------- CSR build ----------------
__global__ void count_deg(const int* __restrict__ ei, int* __restrict__ deg) {
    int e = blockIdx.x * 256 + threadIdx.x;
    if (e >= ET) return;
    int dst = (e < N_EDG) ? ei[N_EDG + e] : (e - N_EDG);
    atomicAdd(&deg[dst], 1);
}

__global__ __launch_bounds__(1024) void scan_offsets(const int* __restrict__ deg,
                                                     int* __restrict__ offs) {
    __shared__ int buf[1024];
    __shared__ int carry_s;
    int t = threadIdx.x;
    if (t == 0) { carry_s = 0; offs[0] = 0; }
    __syncthreads();
    for (int base = 0; base < N_NODES; base += 1024) {
        int i = base + t;
        int v = (i < N_NODES) ? deg[i] : 0;
        buf[t] = v;
        __syncthreads();
        for (int off = 1; off < 1024; off <<= 1) {
            int tmp = (t >= off) ? buf[t - off] : 0;
            __syncthreads();
            buf[t] += tmp;
            __syncthreads();
        }
        int incl = buf[t] + carry_s;
        if (i < N_NODES) offs[i + 1] = incl;
        __syncthreads();
        if (t == 1023) carry_s = incl;
        __syncthreads();
    }
}

__global__ void init_cursor(const int* __restrict__ offs, int* __restrict__ cur) {
    int i = blockIdx.x * 256 + threadIdx.x;
    if (i < N_NODES) cur[i] = offs[i];
}

__global__ void fill_csr(const int* __restrict__ ei, int* __restrict__ cur,
                         int* __restrict__ eids) {
    int e = blockIdx.x * 256 + threadIdx.x;
    if (e >= ET) return;
    int dst = (e < N_EDG) ? ei[N_EDG + e] : (e - N_EDG);
    int pos = atomicAdd(&cur[dst], 1);
    eids[pos] = e;
}

// ---------------- GEMM1: [20000x256] @ [256x512] + b, twice (blockIdx.z) ----------------
#define BM 64
#define BN 64
#define BK 32
__global__ __launch_bounds__(256) void gemm1(const float* __restrict__ x,
        const float* __restrict__ Wl, const float* __restrict__ bl,
        const float* __restrict__ Wr, const float* __restrict__ br,
        float* __restrict__ outl, float* __restrict__ outr) {
    const float* W = (blockIdx.z == 0) ? Wl : Wr;
    const float* b = (blockIdx.z == 0) ? bl : br;
    float* out = (blockIdx.z == 0) ? outl : outr;

    __shared__ float As[BK][BM + 4];  // transposed: As[k][m]
    __shared__ float Bs[BK][BN + 4];

    int row0 = blockIdx.y * BM;
    int col0 = blockIdx.x * BN;
    int tx = threadIdx.x % 16;  // output col group
    int ty = threadIdx.x / 16;  // output row group

    float acc[4][4] = {};

    for (int k0 = 0; k0 < NFE; k0 += BK) {
        // A tile: 64 rows x 32 k, 512 float4s, 2 per thread
        #pragma unroll
        for (int i = 0; i < 2; ++i) {
            int fid = threadIdx.x * 2 + i;
            int r = fid / 8;
            int kk = (fid % 8) * 4;
            float4 v = make_float4(0.f, 0.f, 0.f, 0.f);
            int grow = row0 + r;
            if (grow < N_NODES)
                v = *reinterpret_cast<const float4*>(x + (size_t)grow * NFE + k0 + kk);
            As[kk + 0][r] = v.x; As[kk + 1][r] = v.y;
            As[kk + 2][r] = v.z; As[kk + 3][r] = v.w;
        }
        // B tile: 32 k x 64 cols
        #pragma unroll
        for (int i = 0; i < 2; ++i) {
            int fid = threadIdx.x * 2 + i;
            int kk = fid / 16;
            int c = (fid % 16) * 4;
            float4 v = *reinterpret_cast<const float4*>(W + (size_t)(k0 + kk) * HD + col0 + c);
            *reinterpret_cast<float4*>(&Bs[kk][c]) = v;
        }
        __syncthreads();
        #pragma unroll
        for (int k = 0; k < BK; ++k) {
            float a[4], bb[4];
            *reinterpret_cast<float4*>(a)  = *reinterpret_cast<const float4*>(&As[k][ty * 4]);
            *reinterpret_cast<float4*>(bb) = *reinterpret_cast<const float4*>(&Bs[k][tx * 4]);
            #pragma unroll
            for (int m = 0; m < 4; ++m)
                #pragma unroll
                for (int n = 0; n < 4; ++n)
                    acc[m][n] = fmaf(a[m], bb[n], acc[m][n]);
        }
        __syncthreads();
    }
    #pragma unroll
    for (int m = 0; m < 4; ++m) {
        int grow = row0 + ty * 4 + m;
        if (grow >= N_NODES) continue;
        #pragma unroll
        for (int n = 0; n < 4; ++n) {
            int gcol = col0 + tx * 4 + n;
            out[(size_t)grow * HD + gcol] = acc[m][n] + b[gcol];
        }
    }
}

// ---------------- edge logits layer1: wave per edge ----------------
__global__ __launch_bounds__(256) void edge_logits1(const int* __restrict__ ei,
        const float* __restrict__ xl1, const float* __restrict__ xr1,
        const float* __restrict__ att1, float* __restrict__ e1) {
    int w = (blockIdx.x * 256 + threadIdx.x) >> 6;
    int lane = threadIdx.x & 63;
    if (w >= ET) return;
    int src, dst;
    if (w < N_EDG) { src = ei[w]; dst = ei[N_EDG + w]; }
    else { src = w - N_EDG; dst = src; }
    const float* pl = xl1 + (size_t)src * HD;
    const float* pr = xr1 + (size_t)dst * HD;
    float acc[NH];
    #pragma unroll
    for (int h = 0; h < NH; ++h) {
        float v = lrelu(pl[h * DH + lane] + pr[h * DH + lane]);
        acc[h] = v * att1[h * DH + lane];
    }
    #pragma unroll
    for (int h = 0; h < NH; ++h)
        #pragma unroll
        for (int s = 1; s < 64; s <<= 1) acc[h] += __shfl_xor(acc[h], s);
    if (lane == 0) {
        float* ep = e1 + (size_t)w * NH;
        #pragma unroll
        for (int h = 0; h < NH; ++h) ep[h] = acc[h];
    }
}

// ---------------- per-node softmax + aggregate layer1 (wave per node) ----------------
__global__ __launch_bounds__(256) void node_agg1(const int* __restrict__ offs,
        const int* __restrict__ eids, const int* __restrict__ ei,
        const float* __restrict__ xl1, const float* __restrict__ e1,
        const float* __restrict__ bias1, float* __restrict__ hout) {
    int wid = (blockIdx.x * 256 + threadIdx.x) >> 6;
    int lane = threadIdx.x & 63;
    if (wid >= N_NODES) return;
    int beg = offs[wid], end = offs[wid + 1];

    float mx[NH];
    #pragma unroll
    for (int h = 0; h < NH; ++h) mx[h] = -3.4e38f;
    for (int j = beg + lane; j < end; j += 64) {
        const float* ep = e1 + (size_t)eids[j] * NH;
        #pragma unroll
        for (int h = 0; h < NH; ++h) mx[h] = fmaxf(mx[h], ep[h]);
    }
    #pragma unroll
    for (int h = 0; h < NH; ++h)
        #pragma unroll
        for (int s = 1; s < 64; s <<= 1) mx[h] = fmaxf(mx[h], __shfl_xor(mx[h], s));

    float sm[NH] = {};
    for (int j = beg + lane; j < end; j += 64) {
        const float* ep = e1 + (size_t)eids[j] * NH;
        #pragma unroll
        for (int h = 0; h < NH; ++h) sm[h] += expf(ep[h] - mx[h]);
    }
    #pragma unroll
    for (int h = 0; h < NH; ++h)
        #pragma unroll
        for (int s = 1; s < 64; s <<= 1) sm[h] += __shfl_xor(sm[h], s);

    float inv[NH];
    #pragma unroll
    for (int h = 0; h < NH; ++h) inv[h] = 1.0f / sm[h];

    float acc[NH] = {};
    for (int j = beg; j < end; ++j) {
        int e = eids[j];
        int src = (e < N_EDG) ? ei[e] : (e - N_EDG);
        const float* xs = xl1 + (size_t)src * HD;
        const float* ep = e1 + (size_t)e * NH;
        #pragma unroll
        for (int h = 0; h < NH; ++h) {
            float p = expf(ep[h] - mx[h]) * inv[h];
            acc[h] = fmaf(p, xs[h * DH + lane], acc[h]);
        }
    }
    #pragma unroll
    for (int h = 0; h < NH; ++h) {
        float v = acc[h] + bias1[h * DH + lane];
        hout[(size_t)wid * HD + h * DH + lane] = fmaxf(v, 0.f);
    }
}

// ---------------- GEMM2: [20000x512] @ [512x16] x2 ----------------
__global__ __launch_bounds__(256) void gemm2(const float* __restrict__ h,
        const float* __restrict__ Wl2, const float* __restrict__ bl2,
        const float* __restrict__ Wr2, const float* __restrict__ br2,
        float* __restrict__ xl2, float* __restrict__ xr2) {
    int tx = threadIdx.x % 32;
    int ty = threadIdx.x / 32;
    int row = blockIdx.x * 8 + ty;
    if (row >= N_NODES) return;
    const float* W = (tx < 16) ? Wl2 : Wr2;
    int c = tx & 15;
    const float* hr = h + (size_t)row * HD;
    float acc = 0.f;
    #pragma unroll 8
    for (int k = 0; k < HD; ++k)
        acc = fmaf(hr[k], W[k * NC + c], acc);
    if (tx < 16) xl2[(size_t)row * NC + c] = acc + bl2[c];
    else         xr2[(size_t)row * NC + c] = acc + br2[c];
}

// ---------------- edge logits layer2: 16 lanes per edge ----------------
__global__ __launch_bounds__(256) void edge_logits2(const int* __restrict__ ei,
        const float* __restrict__ xl2, const float* __restrict__ xr2,
        const float* __restrict__ att2, float* __restrict__ e2) {
    int w = (blockIdx.x * 256 + threadIdx.x) >> 6;
    int lane = threadIdx.x & 63;
    int g = lane >> 4, d = lane & 15;
    int e = w * 4 + g;
    if (e >= ET) return;
    int src, dst;
    if (e < N_EDG) { src = ei[e]; dst = ei[N_EDG + e]; }
    else { src = e - N_EDG; dst = src; }
    float v = lrelu(xl2[(size_t)src * NC + d] + xr2[(size_t)dst * NC + d]) * att2[d];
    #pragma unroll
    for (int s = 1; s < 16; s <<= 1) v += __shfl_xor(v, s, 16);
    if (d == 0) e2[e] = v;
}

// ---------------- per-node softmax + aggregate layer2 (wave per node) ----------------
__global__ __launch_bounds__(256) void node_agg2(const int* __restrict__ offs,
        const int* __restrict__ eids, const int* __restrict__ ei,
        const float* __restrict__ xl2, const float* __restrict__ e2,
        const float* __restrict__ bias2, float* __restrict__ out) {
    int wid = (blockIdx.x * 256 + threadIdx.x) >> 6;
    int lane = threadIdx.x & 63;
    if (wid >= N_NODES) return;
    int beg = offs[wid], end = offs[wid + 1];

    float mx = -3.4e38f;
    for (int j = beg + lane; j < end; j += 64) mx = fmaxf(mx, e2[eids[j]]);
    #pragma unroll
    for (int s = 1; s < 64; s <<= 1) mx = fmaxf(mx, __shfl_xor(mx, s));

    float sm = 0.f;
    for (int j = beg + lane; j < end; j += 64) sm += expf(e2[eids[j]] - mx);
    #pragma unroll
    for (int s = 1; s < 64; s <<= 1) sm += __shfl_xor(sm, s);
    float inv = 1.0f / sm;

    int g = lane >> 4, d = lane & 15;
    float acc = 0.f;
    for (int j = beg + g; j < end; j += 4) {
        int e = eids[j];
        int src = (e < N_EDG) ? ei[e] : (e - N_EDG);
        float p = expf(e2[e] - mx) * inv;
        acc = fmaf(p, xl2[(size_t)src * NC + d], acc);
    }
    acc += __shfl_xor(acc, 16);
    acc += __shfl_xor(acc, 32);
    if (lane < 16) out[(size_t)wid * NC + lane] = acc + bias2[lane];
}

// ---------------- launch ----------------
extern "C" void kernel_launch(void* const* d_in, const int* in_sizes, int n_in,
                              void* d_out, int out_size, void* d_ws, size_t ws_size,
                              hipStream_t stream) {
    const float* x     = (const float*)d_in[0];
    const int*   ei    = (const int*)d_in[1];
    const float* W_l1  = (const float*)d_in[2];
    const float* b_l1  = (const float*)d_in[3];
    const float* W_r1  = (const float*)d_in[4];
    const float* b_r1  = (const float*)d_in[5];
    const float* att1  = (const float*)d_in[6];
    const float* bias1 = (const float*)d_in[7];
    const float* W_l2  = (const float*)d_in[8];
    const float* b_l2  = (const float*)d_in[9];
    const float* W_r2  = (const float*)d_in[10];
    const float* b_r2  = (const float*)d_in[11];
    const float* att2  = (const float*)d_in[12];
    const float* bias2 = (const float*)d_in[13];
    float* out = (float*)d_out;

    char* ws = (char*)d_ws;
    float* xl1  = (float*)ws; ws += (size_t)N_NODES * HD * sizeof(float);
    float* xr1  = (float*)ws; ws += (size_t)N_NODES * HD * sizeof(float);
    float* hbuf = (float*)ws; ws += (size_t)N_NODES * HD * sizeof(float);
    float* e1   = (float*)ws; ws += (size_t)ET * NH * sizeof(float);
    float* xl2  = (float*)ws; ws += (size_t)N_NODES * NC * sizeof(float);
    float* xr2  = (float*)ws; ws += (size_t)N_NODES * NC * sizeof(float);
    float* e2   = (float*)ws; ws += (size_t)ET * sizeof(float);
    int* deg    = (int*)ws; ws += (size_t)N_NODES * sizeof(int);
    int* offs   = (int*)ws; ws += (size_t)(N_NODES + 1) * sizeof(int);
    int* cursor = (int*)ws; ws += (size_t)N_NODES * sizeof(int);
    int* eids   = (int*)ws; ws += (size_t)ET * sizeof(int);

    hipMemsetAsync(deg, 0, N_NODES * sizeof(int), stream);
    count_deg<<<(ET + 255) / 256, 256, 0, stream>>>(ei, deg);
    scan_offsets<<<1, 1024, 0, stream>>>(deg, offs);
    init_cursor<<<(N_NODES + 255) / 256, 256, 0, stream>>>(offs, cursor);
    fill_csr<<<(ET + 255) / 256, 256, 0, stream>>>(ei, cursor, eids);

    gemm1<<<dim3(HD / BN, (N_NODES + BM - 1) / BM, 2), 256, 0, stream>>>(
        x, W_l1, b_l1, W_r1, b_r1, xl1, xr1);
    edge_logits1<<<(ET + 3) / 4, 256, 0, stream>>>(ei, xl1, xr1, att1, e1);
    node_agg1<<<(N_NODES + 3) / 4, 256, 0, stream>>>(offs, eids, ei, xl1, e1, bias1, hbuf);

    gemm2<<<(N_NODES + 7) / 8, 256, 0, stream>>>(hbuf, W_l2, b_l2, W_r2, b_r2, xl2, xr2);
    edge_logits2<<<(ET + 15) / 16, 256, 0, stream>>>(ei, xl2, xr2, att2, e2);
    node_agg2<<<(N_NODES + 3) / 4, 256, 0, stream>>>(offs, eids, ei, xl2, e2, bias2, out);
}

// Round 2
// 476.875 us; speedup vs baseline: 1.5274x; 1.5274x over previous
//
#include <hip/hip_runtime.h>
#include <hip/hip_bf16.h>

#define N_NODES 20000
#define N_EDG   320000
#define ET      (N_EDG + N_NODES)   // edges + self loops = 340000
#define NFE     256                 // input feats
#define HD      512                 // HEADS*DIM_H
#define NH      8
#define DH      64
#define NC      16

__device__ __forceinline__ float lrelu(float v) { return v > 0.f ? v : 0.2f * v; }

// ---------------- CSR build ----------------
__global__ void count_deg(const int* __restrict__ ei, int* __restrict__ deg) {
    int e = blockIdx.x * 256 + threadIdx.x;
    if (e >= ET) return;
    int dst = (e < N_EDG) ? ei[N_EDG + e] : (e - N_EDG);
    atomicAdd(&deg[dst], 1);
}

// wave-shfl based scan: 3 barriers per 1024-chunk instead of ~40
__global__ __launch_bounds__(1024) void scan_offsets(const int* __restrict__ deg,
                                                     int* __restrict__ offs) {
    __shared__ int wsum[16];
    __shared__ int carry_s;
    int t = threadIdx.x;
    int wid = t >> 6, lane = t & 63;
    if (t == 0) { carry_s = 0; offs[0] = 0; }
    __syncthreads();
    for (int base = 0; base < N_NODES; base += 1024) {
        int i = base + t;
        int v = (i < N_NODES) ? deg[i] : 0;
        int sv = v;
        #pragma unroll
        for (int off = 1; off < 64; off <<= 1) {
            int n = __shfl_up(sv, off);
            if (lane >= off) sv += n;
        }
        if (lane == 63) wsum[wid] = sv;
        __syncthreads();
        int wpre = 0;
        #pragma unroll
        for (int w = 0; w < 16; ++w) wpre += (w < wid) ? wsum[w] : 0;
        int incl = sv + wpre + carry_s;
        if (i < N_NODES) offs[i + 1] = incl;
        __syncthreads();
        if (t == 1023) carry_s = incl;
        __syncthreads();
    }
}

__global__ void init_cursor(const int* __restrict__ offs, int* __restrict__ cur) {
    int i = blockIdx.x * 256 + threadIdx.x;
    if (i < N_NODES) cur[i] = offs[i];
}

// store SRC node id directly in CSR payload (fused kernels never need edge id)
__global__ void fill_csr(const int* __restrict__ ei, int* __restrict__ cur,
                         int* __restrict__ esrc) {
    int e = blockIdx.x * 256 + threadIdx.x;
    if (e >= ET) return;
    int src, dst;
    if (e < N_EDG) { src = ei[e]; dst = ei[N_EDG + e]; }
    else { src = e - N_EDG; dst = src; }
    int pos = atomicAdd(&cur[dst], 1);
    esrc[pos] = src;
}

// ---------------- GEMM1: [20000x256] @ [256x512] + b, twice (blockIdx.z) ----------------
#define BM 128
#define BN 64
#define BK 16
__global__ __launch_bounds__(256) void gemm1(const float* __restrict__ x,
        const float* __restrict__ Wl, const float* __restrict__ bl,
        const float* __restrict__ Wr, const float* __restrict__ br,
        float* __restrict__ outl, float* __restrict__ outr) {
    const float* W = (blockIdx.z == 0) ? Wl : Wr;
    const float* b = (blockIdx.z == 0) ? bl : br;
    float* out = (blockIdx.z == 0) ? outl : outr;

    __shared__ float As[BK][BM + 4];  // transposed: As[k][m]
    __shared__ float Bs[BK][BN + 4];

    int row0 = blockIdx.y * BM;
    int col0 = blockIdx.x * BN;
    int ty = threadIdx.x >> 4;   // 0..15 -> rows ty*8..+7
    int tx = threadIdx.x & 15;   // 0..15 -> cols tx*4..+3

    float acc[8][4] = {};

    for (int k0 = 0; k0 < NFE; k0 += BK) {
        // A tile: 128 rows x 16 k = 512 float4s, 2 per thread
        #pragma unroll
        for (int i = 0; i < 2; ++i) {
            int fid = threadIdx.x + i * 256;   // 0..511
            int r = fid >> 2;                  // 0..127
            int kk = (fid & 3) * 4;
            float4 v = make_float4(0.f, 0.f, 0.f, 0.f);
            int grow = row0 + r;
            if (grow < N_NODES)
                v = *reinterpret_cast<const float4*>(x + (size_t)grow * NFE + k0 + kk);
            As[kk + 0][r] = v.x; As[kk + 1][r] = v.y;
            As[kk + 2][r] = v.z; As[kk + 3][r] = v.w;
        }
        // B tile: 16 k x 64 cols = 256 float4s, 1 per thread
        {
            int kk = threadIdx.x >> 4;
            int c  = (threadIdx.x & 15) * 4;
            *reinterpret_cast<float4*>(&Bs[kk][c]) =
                *reinterpret_cast<const float4*>(W + (size_t)(k0 + kk) * HD + col0 + c);
        }
        __syncthreads();
        #pragma unroll
        for (int k = 0; k < BK; ++k) {
            float a[8], bb[4];
            *reinterpret_cast<float4*>(&a[0]) = *reinterpret_cast<const float4*>(&As[k][ty * 8]);
            *reinterpret_cast<float4*>(&a[4]) = *reinterpret_cast<const float4*>(&As[k][ty * 8 + 4]);
            *reinterpret_cast<float4*>(&bb[0]) = *reinterpret_cast<const float4*>(&Bs[k][tx * 4]);
            #pragma unroll
            for (int m = 0; m < 8; ++m)
                #pragma unroll
                for (int n = 0; n < 4; ++n)
                    acc[m][n] = fmaf(a[m], bb[n], acc[m][n]);
        }
        __syncthreads();
    }
    #pragma unroll
    for (int m = 0; m < 8; ++m) {
        int grow = row0 + ty * 8 + m;
        if (grow >= N_NODES) continue;
        int gcol = col0 + tx * 4;
        float4 v;
        v.x = acc[m][0] + b[gcol + 0];
        v.y = acc[m][1] + b[gcol + 1];
        v.z = acc[m][2] + b[gcol + 2];
        v.w = acc[m][3] + b[gcol + 3];
        *reinterpret_cast<float4*>(out + (size_t)grow * HD + gcol) = v;
    }
}

// ---------------- fused layer1: logits + online softmax + aggregate + bias + relu ----
// One wave per node. lane = h*8 + dim_block; each lane owns 8 contiguous dims
// (lane*8 .. lane*8+7) of the 512-wide feature row. Per-edge reduce needs only
// 3 shfl_xor steps (within 8-lane head group), all 8 heads in parallel.
__global__ __launch_bounds__(256) void fused1(const int* __restrict__ offs,
        const int* __restrict__ esrc,
        const float* __restrict__ xl1, const float* __restrict__ xr1,
        const float* __restrict__ att1, const float* __restrict__ bias1,
        float* __restrict__ hout) {
    int wid = (blockIdx.x * 256 + threadIdx.x) >> 6;
    int lane = threadIdx.x & 63;
    if (wid >= N_NODES) return;
    int beg = offs[wid], end = offs[wid + 1];

    float att[8], xr[8];
    *reinterpret_cast<float4*>(&att[0]) = *reinterpret_cast<const float4*>(att1 + lane * 8);
    *reinterpret_cast<float4*>(&att[4]) = *reinterpret_cast<const float4*>(att1 + lane * 8 + 4);
    const float* xrp = xr1 + (size_t)wid * HD + lane * 8;
    *reinterpret_cast<float4*>(&xr[0]) = *reinterpret_cast<const float4*>(xrp);
    *reinterpret_cast<float4*>(&xr[4]) = *reinterpret_cast<const float4*>(xrp + 4);

    float m = -3.4e38f, s = 0.f;
    float acc[8] = {};

    // prefetch first edge
    float xs[8];
    {
        int src = esrc[beg];
        const float* xp = xl1 + (size_t)src * HD + lane * 8;
        *reinterpret_cast<float4*>(&xs[0]) = *reinterpret_cast<const float4*>(xp);
        *reinterpret_cast<float4*>(&xs[4]) = *reinterpret_cast<const float4*>(xp + 4);
    }

    for (int j = beg; j < end; ++j) {
        float cx[8];
        #pragma unroll
        for (int q = 0; q < 8; ++q) cx[q] = xs[q];
        if (j + 1 < end) {
            int ns = esrc[j + 1];
            const float* np = xl1 + (size_t)ns * HD + lane * 8;
            *reinterpret_cast<float4*>(&xs[0]) = *reinterpret_cast<const float4*>(np);
            *reinterpret_cast<float4*>(&xs[4]) = *reinterpret_cast<const float4*>(np + 4);
        }
        float v = 0.f;
        #pragma unroll
        for (int q = 0; q < 8; ++q) {
            float t = cx[q] + xr[q];
            t = t > 0.f ? t : 0.2f * t;
            v = fmaf(t, att[q], v);
        }
        v += __shfl_xor(v, 1);
        v += __shfl_xor(v, 2);
        v += __shfl_xor(v, 4);
        float nm = fmaxf(m, v);
        float sc = __expf(m - nm);
        float p  = __expf(v - nm);
        s = s * sc + p;
        #pragma unroll
        for (int q = 0; q < 8; ++q) acc[q] = fmaf(acc[q], sc, p * cx[q]);
        m = nm;
    }

    float inv = 1.0f / s;
    float o[8];
    #pragma unroll
    for (int q = 0; q < 8; ++q) {
        float bi = bias1[lane * 8 + q];
        o[q] = fmaxf(fmaf(acc[q], inv, bi), 0.f);  // +bias, relu
    }
    float* op = hout + (size_t)wid * HD + lane * 8;
    *reinterpret_cast<float4*>(op)     = *reinterpret_cast<float4*>(&o[0]);
    *reinterpret_cast<float4*>(op + 4) = *reinterpret_cast<float4*>(&o[4]);
}

// ---------------- GEMM2: [20000x512] @ [512x16] x2 ----------------
__global__ __launch_bounds__(256) void gemm2(const float* __restrict__ h,
        const float* __restrict__ Wl2, const float* __restrict__ bl2,
        const float* __restrict__ Wr2, const float* __restrict__ br2,
        float* __restrict__ xl2, float* __restrict__ xr2) {
    int tx = threadIdx.x % 32;
    int ty = threadIdx.x / 32;
    int row = blockIdx.x * 8 + ty;
    if (row >= N_NODES) return;
    const float* W = (tx < 16) ? Wl2 : Wr2;
    int c = tx & 15;
    const float* hr = h + (size_t)row * HD;
    float acc = 0.f;
    #pragma unroll 8
    for (int k = 0; k < HD; ++k)
        acc = fmaf(hr[k], W[k * NC + c], acc);
    if (tx < 16) xl2[(size_t)row * NC + c] = acc + bl2[c];
    else         xr2[(size_t)row * NC + c] = acc + br2[c];
}

// ---------------- fused layer2: logits + online softmax + aggregate + bias ------------
// One wave per node; 4 edge-groups x 16 lanes. Cross-group merge at the end.
__global__ __launch_bounds__(256) void fused2(const int* __restrict__ offs,
        const int* __restrict__ esrc,
        const float* __restrict__ xl2, const float* __restrict__ xr2,
        const float* __restrict__ att2, const float* __restrict__ bias2,
        float* __restrict__ out) {
    int wid = (blockIdx.x * 256 + threadIdx.x) >> 6;
    int lane = threadIdx.x & 63;
    if (wid >= N_NODES) return;
    int g = lane >> 4, d = lane & 15;
    int beg = offs[wid], end = offs[wid + 1];

    float xr = xr2[(size_t)wid * NC + d];
    float at = att2[d];
    float m = -3.4e38f, s = 0.f, acc = 0.f;

    for (int j = beg + g; j < end; j += 4) {
        int src = esrc[j];
        float xs = xl2[(size_t)src * NC + d];
        float t = xs + xr;
        t = t > 0.f ? t : 0.2f * t;
        float v = t * at;
        v += __shfl_xor(v, 1);
        v += __shfl_xor(v, 2);
        v += __shfl_xor(v, 4);
        v += __shfl_xor(v, 8);
        float nm = fmaxf(m, v);
        float sc = __expf(m - nm), p = __expf(v - nm);
        s = s * sc + p;
        acc = fmaf(acc, sc, p * xs);
        m = nm;
    }
    // merge the 4 groups' (m, s, acc)
    #pragma unroll
    for (int off = 16; off < 64; off <<= 1) {
        float om = __shfl_xor(m, off);
        float os = __shfl_xor(s, off);
        float oa = __shfl_xor(acc, off);
        float nm = fmaxf(m, om);
        float c1 = __expf(m - nm), c2 = __expf(om - nm);
        s = s * c1 + os * c2;
        acc = acc * c1 + oa * c2;
        m = nm;
    }
    if (lane < 16) out[(size_t)wid * NC + d] = acc / s + bias2[d];
}

// ---------------- launch ----------------
extern "C" void kernel_launch(void* const* d_in, const int* in_sizes, int n_in,
                              void* d_out, int out_size, void* d_ws, size_t ws_size,
                              hipStream_t stream) {
    const float* x     = (const float*)d_in[0];
    const int*   ei    = (const int*)d_in[1];
    const float* W_l1  = (const float*)d_in[2];
    const float* b_l1  = (const float*)d_in[3];
    const float* W_r1  = (const float*)d_in[4];
    const float* b_r1  = (const float*)d_in[5];
    const float* att1  = (const float*)d_in[6];
    const float* bias1 = (const float*)d_in[7];
    const float* W_l2  = (const float*)d_in[8];
    const float* b_l2  = (const float*)d_in[9];
    const float* W_r2  = (const float*)d_in[10];
    const float* b_r2  = (const float*)d_in[11];
    const float* att2  = (const float*)d_in[12];
    const float* bias2 = (const float*)d_in[13];
    float* out = (float*)d_out;

    char* ws = (char*)d_ws;
    float* xl1  = (float*)ws; ws += (size_t)N_NODES * HD * sizeof(float);
    float* xr1  = (float*)ws; ws += (size_t)N_NODES * HD * sizeof(float);
    float* hbuf = (float*)ws; ws += (size_t)N_NODES * HD * sizeof(float);
    float* xl2  = (float*)ws; ws += (size_t)N_NODES * NC * sizeof(float);
    float* xr2  = (float*)ws; ws += (size_t)N_NODES * NC * sizeof(float);
    int* deg    = (int*)ws; ws += (size_t)N_NODES * sizeof(int);
    int* offs   = (int*)ws; ws += (size_t)(N_NODES + 1) * sizeof(int);
    int* cursor = (int*)ws; ws += (size_t)N_NODES * sizeof(int);
    int* esrc   = (int*)ws; ws += (size_t)ET * sizeof(int);

    hipMemsetAsync(deg, 0, N_NODES * sizeof(int), stream);
    count_deg<<<(ET + 255) / 256, 256, 0, stream>>>(ei, deg);
    scan_offsets<<<1, 1024, 0, stream>>>(deg, offs);
    init_cursor<<<(N_NODES + 255) / 256, 256, 0, stream>>>(offs, cursor);
    fill_csr<<<(ET + 255) / 256, 256, 0, stream>>>(ei, cursor, esrc);

    gemm1<<<dim3(HD / BN, (N_NODES + BM - 1) / BM, 2), 256, 0, stream>>>(
        x, W_l1, b_l1, W_r1, b_r1, xl1, xr1);
    fused1<<<(N_NODES + 3) / 4, 256, 0, stream>>>(offs, esrc, xl1, xr1, att1, bias1, hbuf);

    gemm2<<<(N_NODES + 7) / 8, 256, 0, stream>>>(hbuf, W_l2, b_l2, W_r2, b_r2, xl2, xr2);
    fused2<<<(N_NODES + 3) / 4, 256, 0, stream>>>(offs, esrc, xl2, xr2, att2, bias2, out);
}

// Round 3
// 458.760 us; speedup vs baseline: 1.5877x; 1.0395x over previous
//
#include <hip/hip_runtime.h>
#include <hip/hip_bf16.h>

#define N_NODES 20000
#define N_EDG   320000
#define ET      (N_EDG + N_NODES)   // edges + self loops = 340000
#define NFE     256                 // input feats
#define HD      512                 // HEADS*DIM_H
#define NH      8
#define DH      64
#define NC      16

__device__ __forceinline__ float lrelu(float v) { return v > 0.f ? v : 0.2f * v; }

// ---------------- CSR build ----------------
__global__ void count_deg(const int* __restrict__ ei, int* __restrict__ deg) {
    int e = blockIdx.x * 256 + threadIdx.x;
    if (e >= ET) return;
    int dst = (e < N_EDG) ? ei[N_EDG + e] : (e - N_EDG);
    atomicAdd(&deg[dst], 1);
}

// wave-shfl based scan; also writes cursor = exclusive prefix (saves a kernel)
__global__ __launch_bounds__(1024) void scan_offsets(const int* __restrict__ deg,
                                                     int* __restrict__ offs,
                                                     int* __restrict__ cur) {
    __shared__ int wsum[16];
    __shared__ int carry_s;
    int t = threadIdx.x;
    int wid = t >> 6, lane = t & 63;
    if (t == 0) { carry_s = 0; offs[0] = 0; }
    __syncthreads();
    for (int base = 0; base < N_NODES; base += 1024) {
        int i = base + t;
        int v = (i < N_NODES) ? deg[i] : 0;
        int sv = v;
        #pragma unroll
        for (int off = 1; off < 64; off <<= 1) {
            int n = __shfl_up(sv, off);
            if (lane >= off) sv += n;
        }
        if (lane == 63) wsum[wid] = sv;
        __syncthreads();
        int wpre = 0;
        #pragma unroll
        for (int w = 0; w < 16; ++w) wpre += (w < wid) ? wsum[w] : 0;
        int incl = sv + wpre + carry_s;
        if (i < N_NODES) {
            offs[i + 1] = incl;
            cur[i] = incl - v;   // exclusive prefix
        }
        __syncthreads();
        if (t == 1023) carry_s = incl;
        __syncthreads();
    }
}

// store SRC node id directly in CSR payload
__global__ void fill_csr(const int* __restrict__ ei, int* __restrict__ cur,
                         int* __restrict__ esrc) {
    int e = blockIdx.x * 256 + threadIdx.x;
    if (e >= ET) return;
    int src, dst;
    if (e < N_EDG) { src = ei[e]; dst = ei[N_EDG + e]; }
    else { src = e - N_EDG; dst = src; }
    int pos = atomicAdd(&cur[dst], 1);
    esrc[pos] = src;
}

// ---------------- GEMM1: [20000x256] @ [256x512] + b, twice ----------------
// Flat grid with XCD-bijective swizzle so all 8 col-blocks of one 128-row
// x-panel run on the SAME XCD -> panel fetched once per L2 (was 8x).
#define BM 128
#define BN 64
#define BK 16
#define ROWP ((N_NODES + BM - 1) / BM)      // 157 row panels
#define G1_NWG (8 * ROWP * 2)               // 2512
__global__ __launch_bounds__(256) void gemm1(const float* __restrict__ x,
        const float* __restrict__ Wl, const float* __restrict__ bl,
        const float* __restrict__ Wr, const float* __restrict__ br,
        float* __restrict__ outl, float* __restrict__ outr) {
    // bijective XCD swizzle: q = G1_NWG/8 = 314, r = 0
    int flat = blockIdx.x;
    int xcd = flat & 7;
    int wgid = xcd * (G1_NWG / 8) + (flat >> 3);
    int z = wgid / (8 * ROWP);
    int rem = wgid - z * (8 * ROWP);
    int rowp = rem >> 3;        // 0..156  (consecutive wgids share rowp)
    int colb = rem & 7;         // 0..7

    const float* W = (z == 0) ? Wl : Wr;
    const float* b = (z == 0) ? bl : br;
    float* out = (z == 0) ? outl : outr;

    __shared__ float As[BK][BM + 4];  // transposed: As[k][m]
    __shared__ float Bs[BK][BN + 4];

    int row0 = rowp * BM;
    int col0 = colb * BN;
    int ty = threadIdx.x >> 4;   // 0..15 -> rows ty*8..+7
    int tx = threadIdx.x & 15;   // 0..15 -> cols tx*4..+3

    float acc[8][4] = {};

    for (int k0 = 0; k0 < NFE; k0 += BK) {
        #pragma unroll
        for (int i = 0; i < 2; ++i) {
            int fid = threadIdx.x + i * 256;   // 0..511
            int r = fid >> 2;                  // 0..127
            int kk = (fid & 3) * 4;
            float4 v = make_float4(0.f, 0.f, 0.f, 0.f);
            int grow = row0 + r;
            if (grow < N_NODES)
                v = *reinterpret_cast<const float4*>(x + (size_t)grow * NFE + k0 + kk);
            As[kk + 0][r] = v.x; As[kk + 1][r] = v.y;
            As[kk + 2][r] = v.z; As[kk + 3][r] = v.w;
        }
        {
            int kk = threadIdx.x >> 4;
            int c  = (threadIdx.x & 15) * 4;
            *reinterpret_cast<float4*>(&Bs[kk][c]) =
                *reinterpret_cast<const float4*>(W + (size_t)(k0 + kk) * HD + col0 + c);
        }
        __syncthreads();
        #pragma unroll
        for (int k = 0; k < BK; ++k) {
            float a[8], bb[4];
            *reinterpret_cast<float4*>(&a[0]) = *reinterpret_cast<const float4*>(&As[k][ty * 8]);
            *reinterpret_cast<float4*>(&a[4]) = *reinterpret_cast<const float4*>(&As[k][ty * 8 + 4]);
            *reinterpret_cast<float4*>(&bb[0]) = *reinterpret_cast<const float4*>(&Bs[k][tx * 4]);
            #pragma unroll
            for (int m = 0; m < 8; ++m)
                #pragma unroll
                for (int n = 0; n < 4; ++n)
                    acc[m][n] = fmaf(a[m], bb[n], acc[m][n]);
        }
        __syncthreads();
    }
    #pragma unroll
    for (int m = 0; m < 8; ++m) {
        int grow = row0 + ty * 8 + m;
        if (grow >= N_NODES) continue;
        int gcol = col0 + tx * 4;
        float4 v;
        v.x = acc[m][0] + b[gcol + 0];
        v.y = acc[m][1] + b[gcol + 1];
        v.z = acc[m][2] + b[gcol + 2];
        v.w = acc[m][3] + b[gcol + 3];
        *reinterpret_cast<float4*>(out + (size_t)grow * HD + gcol) = v;
    }
}

// ---------------- fused layer1: logits + online softmax + aggregate + bias + relu ----
__global__ __launch_bounds__(256) void fused1(const int* __restrict__ offs,
        const int* __restrict__ esrc,
        const float* __restrict__ xl1, const float* __restrict__ xr1,
        const float* __restrict__ att1, const float* __restrict__ bias1,
        float* __restrict__ hout) {
    int wid = (blockIdx.x * 256 + threadIdx.x) >> 6;
    int lane = threadIdx.x & 63;
    if (wid >= N_NODES) return;
    int beg = offs[wid], end = offs[wid + 1];

    float att[8], xr[8];
    *reinterpret_cast<float4*>(&att[0]) = *reinterpret_cast<const float4*>(att1 + lane * 8);
    *reinterpret_cast<float4*>(&att[4]) = *reinterpret_cast<const float4*>(att1 + lane * 8 + 4);
    const float* xrp = xr1 + (size_t)wid * HD + lane * 8;
    *reinterpret_cast<float4*>(&xr[0]) = *reinterpret_cast<const float4*>(xrp);
    *reinterpret_cast<float4*>(&xr[4]) = *reinterpret_cast<const float4*>(xrp + 4);

    float m = -3.4e38f, s = 0.f;
    float acc[8] = {};

    float xs[8];
    {
        int src = esrc[beg];
        const float* xp = xl1 + (size_t)src * HD + lane * 8;
        *reinterpret_cast<float4*>(&xs[0]) = *reinterpret_cast<const float4*>(xp);
        *reinterpret_cast<float4*>(&xs[4]) = *reinterpret_cast<const float4*>(xp + 4);
    }

    for (int j = beg; j < end; ++j) {
        float cx[8];
        #pragma unroll
        for (int q = 0; q < 8; ++q) cx[q] = xs[q];
        if (j + 1 < end) {
            int ns = esrc[j + 1];
            const float* np = xl1 + (size_t)ns * HD + lane * 8;
            *reinterpret_cast<float4*>(&xs[0]) = *reinterpret_cast<const float4*>(np);
            *reinterpret_cast<float4*>(&xs[4]) = *reinterpret_cast<const float4*>(np + 4);
        }
        float v = 0.f;
        #pragma unroll
        for (int q = 0; q < 8; ++q) {
            float t = cx[q] + xr[q];
            t = t > 0.f ? t : 0.2f * t;
            v = fmaf(t, att[q], v);
        }
        v += __shfl_xor(v, 1);
        v += __shfl_xor(v, 2);
        v += __shfl_xor(v, 4);
        float nm = fmaxf(m, v);
        float sc = __expf(m - nm);
        float p  = __expf(v - nm);
        s = s * sc + p;
        #pragma unroll
        for (int q = 0; q < 8; ++q) acc[q] = fmaf(acc[q], sc, p * cx[q]);
        m = nm;
    }

    float inv = 1.0f / s;
    float o[8];
    #pragma unroll
    for (int q = 0; q < 8; ++q) {
        float bi = bias1[lane * 8 + q];
        o[q] = fmaxf(fmaf(acc[q], inv, bi), 0.f);
    }
    float* op = hout + (size_t)wid * HD + lane * 8;
    *reinterpret_cast<float4*>(op)     = *reinterpret_cast<float4*>(&o[0]);
    *reinterpret_cast<float4*>(op + 4) = *reinterpret_cast<float4*>(&o[4]);
}

// ---------------- GEMM2: [20000x512] @ [512x16] x2 ----------------
__global__ __launch_bounds__(256) void gemm2(const float* __restrict__ h,
        const float* __restrict__ Wl2, const float* __restrict__ bl2,
        const float* __restrict__ Wr2, const float* __restrict__ br2,
        float* __restrict__ xl2, float* __restrict__ xr2) {
    int tx = threadIdx.x % 32;
    int ty = threadIdx.x / 32;
    int row = blockIdx.x * 8 + ty;
    if (row >= N_NODES) return;
    const float* W = (tx < 16) ? Wl2 : Wr2;
    int c = tx & 15;
    const float4* hr4 = reinterpret_cast<const float4*>(h + (size_t)row * HD);
    float acc = 0.f;
    #pragma unroll 4
    for (int k4 = 0; k4 < HD / 4; ++k4) {
        float4 v = hr4[k4];
        int k = k4 * 4;
        acc = fmaf(v.x, W[(k + 0) * NC + c], acc);
        acc = fmaf(v.y, W[(k + 1) * NC + c], acc);
        acc = fmaf(v.z, W[(k + 2) * NC + c], acc);
        acc = fmaf(v.w, W[(k + 3) * NC + c], acc);
    }
    if (tx < 16) xl2[(size_t)row * NC + c] = acc + bl2[c];
    else         xr2[(size_t)row * NC + c] = acc + br2[c];
}

// ---------------- fused layer2 ----------------
__global__ __launch_bounds__(256) void fused2(const int* __restrict__ offs,
        const int* __restrict__ esrc,
        const float* __restrict__ xl2, const float* __restrict__ xr2,
        const float* __restrict__ att2, const float* __restrict__ bias2,
        float* __restrict__ out) {
    int wid = (blockIdx.x * 256 + threadIdx.x) >> 6;
    int lane = threadIdx.x & 63;
    if (wid >= N_NODES) return;
    int g = lane >> 4, d = lane & 15;
    int beg = offs[wid], end = offs[wid + 1];

    float xr = xr2[(size_t)wid * NC + d];
    float at = att2[d];
    float m = -3.4e38f, s = 0.f, acc = 0.f;

    for (int j = beg + g; j < end; j += 4) {
        int src = esrc[j];
        float xs = xl2[(size_t)src * NC + d];
        float t = xs + xr;
        t = t > 0.f ? t : 0.2f * t;
        float v = t * at;
        v += __shfl_xor(v, 1);
        v += __shfl_xor(v, 2);
        v += __shfl_xor(v, 4);
        v += __shfl_xor(v, 8);
        float nm = fmaxf(m, v);
        float sc = __expf(m - nm), p = __expf(v - nm);
        s = s * sc + p;
        acc = fmaf(acc, sc, p * xs);
        m = nm;
    }
    #pragma unroll
    for (int off = 16; off < 64; off <<= 1) {
        float om = __shfl_xor(m, off);
        float os = __shfl_xor(s, off);
        float oa = __shfl_xor(acc, off);
        float nm = fmaxf(m, om);
        float c1 = __expf(m - nm), c2 = __expf(om - nm);
        s = s * c1 + os * c2;
        acc = acc * c1 + oa * c2;
        m = nm;
    }
    if (lane < 16) out[(size_t)wid * NC + d] = acc / s + bias2[d];
}

// ---------------- launch ----------------
extern "C" void kernel_launch(void* const* d_in, const int* in_sizes, int n_in,
                              void* d_out, int out_size, void* d_ws, size_t ws_size,
                              hipStream_t stream) {
    const float* x     = (const float*)d_in[0];
    const int*   ei    = (const int*)d_in[1];
    const float* W_l1  = (const float*)d_in[2];
    const float* b_l1  = (const float*)d_in[3];
    const float* W_r1  = (const float*)d_in[4];
    const float* b_r1  = (const float*)d_in[5];
    const float* att1  = (const float*)d_in[6];
    const float* bias1 = (const float*)d_in[7];
    const float* W_l2  = (const float*)d_in[8];
    const float* b_l2  = (const float*)d_in[9];
    const float* W_r2  = (const float*)d_in[10];
    const float* b_r2  = (const float*)d_in[11];
    const float* att2  = (const float*)d_in[12];
    const float* bias2 = (const float*)d_in[13];
    float* out = (float*)d_out;

    char* ws = (char*)d_ws;
    float* xl1  = (float*)ws; ws += (size_t)N_NODES * HD * sizeof(float);
    float* xr1  = (float*)ws; ws += (size_t)N_NODES * HD * sizeof(float);
    float* hbuf = (float*)ws; ws += (size_t)N_NODES * HD * sizeof(float);
    float* xl2  = (float*)ws; ws += (size_t)N_NODES * NC * sizeof(float);
    float* xr2  = (float*)ws; ws += (size_t)N_NODES * NC * sizeof(float);
    int* deg    = (int*)ws; ws += (size_t)N_NODES * sizeof(int);
    int* offs   = (int*)ws; ws += (size_t)(N_NODES + 1) * sizeof(int);
    int* cursor = (int*)ws; ws += (size_t)N_NODES * sizeof(int);
    int* esrc   = (int*)ws; ws += (size_t)ET * sizeof(int);

    hipMemsetAsync(deg, 0, N_NODES * sizeof(int), stream);
    count_deg<<<(ET + 255) / 256, 256, 0, stream>>>(ei, deg);
    scan_offsets<<<1, 1024, 0, stream>>>(deg, offs, cursor);
    fill_csr<<<(ET + 255) / 256, 256, 0, stream>>>(ei, cursor, esrc);

    gemm1<<<G1_NWG, 256, 0, stream>>>(x, W_l1, b_l1, W_r1, b_r1, xl1, xr1);
    fused1<<<(N_NODES + 3) / 4, 256, 0, stream>>>(offs, esrc, xl1, xr1, att1, bias1, hbuf);

    gemm2<<<(N_NODES + 7) / 8, 256, 0, stream>>>(hbuf, W_l2, b_l2, W_r2, b_r2, xl2, xr2);
    fused2<<<(N_NODES + 3) / 4, 256, 0, stream>>>(offs, esrc, xl2, xr2, att2, bias2, out);
}

// Round 4
// 430.382 us; speedup vs baseline: 1.6924x; 1.0659x over previous
//
#include <hip/hip_runtime.h>
#include <hip/hip_bf16.h>
#include <stdint.h>

#define N_NODES 20000
#define MPAD    20096               // 157 * 128 padded rows for MFMA panels
#define N_EDG   320000
#define ET      (N_EDG + N_NODES)   // 340000
#define NFE     256
#define HD      512
#define NH      8
#define DH      64
#define NC      16

typedef __attribute__((ext_vector_type(8))) short short8;
typedef __attribute__((ext_vector_type(4))) float f32x4;

#define AS1 __attribute__((address_space(1)))
#define AS3 __attribute__((address_space(3)))

__device__ __forceinline__ unsigned short f2bf(float f) {
    unsigned u = __float_as_uint(f);
    return (unsigned short)((u + 0x7FFFu + ((u >> 16) & 1u)) >> 16);
}
__device__ __forceinline__ float bf2f(unsigned short s) {
    return __uint_as_float(((unsigned)s) << 16);
}

// ---------------- CSR build ----------------
__global__ void count_deg(const int* __restrict__ ei, int* __restrict__ deg) {
    int e = blockIdx.x * 256 + threadIdx.x;
    if (e >= ET) return;
    int dst = (e < N_EDG) ? ei[N_EDG + e] : (e - N_EDG);
    atomicAdd(&deg[dst], 1);
}

__global__ __launch_bounds__(1024) void scan_offsets(const int* __restrict__ deg,
                                                     int* __restrict__ offs,
                                                     int* __restrict__ cur) {
    __shared__ int wsum[16];
    __shared__ int carry_s;
    int t = threadIdx.x;
    int wid = t >> 6, lane = t & 63;
    if (t == 0) { carry_s = 0; offs[0] = 0; }
    __syncthreads();
    for (int base = 0; base < N_NODES; base += 1024) {
        int i = base + t;
        int v = (i < N_NODES) ? deg[i] : 0;
        int sv = v;
        #pragma unroll
        for (int off = 1; off < 64; off <<= 1) {
            int n = __shfl_up(sv, off);
            if (lane >= off) sv += n;
        }
        if (lane == 63) wsum[wid] = sv;
        __syncthreads();
        int wpre = 0;
        #pragma unroll
        for (int w = 0; w < 16; ++w) wpre += (w < wid) ? wsum[w] : 0;
        int incl = sv + wpre + carry_s;
        if (i < N_NODES) {
            offs[i + 1] = incl;
            cur[i] = incl - v;
        }
        __syncthreads();
        if (t == 1023) carry_s = incl;
        __syncthreads();
    }
}

__global__ void fill_csr(const int* __restrict__ ei, int* __restrict__ cur,
                         int* __restrict__ esrc) {
    int e = blockIdx.x * 256 + threadIdx.x;
    if (e >= ET) return;
    int src, dst;
    if (e < N_EDG) { src = ei[e]; dst = ei[N_EDG + e]; }
    else { src = e - N_EDG; dst = src; }
    int pos = atomicAdd(&cur[dst], 1);
    esrc[pos] = src;
}

// ---------------- split fp32 -> bf16 hi/lo ----------------
__global__ __launch_bounds__(256) void split_x(const float* __restrict__ x,
        unsigned short* __restrict__ xh, unsigned short* __restrict__ xl) {
    int i = (blockIdx.x * 256 + threadIdx.x) * 4;
    if (i >= N_NODES * NFE) return;
    float4 v = *reinterpret_cast<const float4*>(x + i);
    ushort4 h, l;
    h.x = f2bf(v.x); l.x = f2bf(v.x - bf2f(h.x));
    h.y = f2bf(v.y); l.y = f2bf(v.y - bf2f(h.y));
    h.z = f2bf(v.z); l.z = f2bf(v.z - bf2f(h.z));
    h.w = f2bf(v.w); l.w = f2bf(v.w - bf2f(h.w));
    *reinterpret_cast<ushort4*>(xh + i) = h;
    *reinterpret_cast<ushort4*>(xl + i) = l;
}

// split + transpose W [256x512] -> Wt [512][256] (k contiguous), both matrices
__global__ __launch_bounds__(256) void split_w(const float* __restrict__ Wl,
        const float* __restrict__ Wr, unsigned short* __restrict__ Wth,
        unsigned short* __restrict__ Wtl) {
    const float* W = blockIdx.y ? Wr : Wl;
    unsigned short* oh = Wth + (size_t)blockIdx.y * (HD * NFE);
    unsigned short* ol = Wtl + (size_t)blockIdx.y * (HD * NFE);
    int i = blockIdx.x * 256 + threadIdx.x;
    if (i >= NFE * HD) return;
    int k = i >> 9, n = i & 511;
    float v = W[i];
    unsigned short h = f2bf(v), l = f2bf(v - bf2f(h));
    oh[n * NFE + k] = h;
    ol[n * NFE + k] = l;
}

// ---------------- GEMM1 via split-bf16 MFMA ----------------
// C = xh@Wh + xh@Wl + xl@Wh  (fp32 accum; al*bl dropped, ~2^-17 rel)
// tile 128x64, BK=32, 4 waves each 64x32 (4x2 frags of 16x16x32)
#define ROWP 157
#define G1_NWG (8 * ROWP * 2)   // 2512; /8 = 314 exactly -> bijective swizzle
__global__ __launch_bounds__(256) void gemm1m(
        const unsigned short* __restrict__ xh, const unsigned short* __restrict__ xl,
        const unsigned short* __restrict__ Wth, const unsigned short* __restrict__ Wtl,
        const float* __restrict__ bl, const float* __restrict__ br,
        float* __restrict__ outl, float* __restrict__ outr) {
    __shared__ short Ah[4 * 128 * 8], Al[4 * 128 * 8];   // [kb][row][8]
    __shared__ short Bh[4 * 64 * 8],  Blo[4 * 64 * 8];   // [kb][n][8]

    int flat = blockIdx.x;
    int wgid = (flat & 7) * (G1_NWG / 8) + (flat >> 3);
    int z = wgid / (8 * ROWP);
    int rem = wgid - z * (8 * ROWP);
    int rowp = rem >> 3, colb = rem & 7;
    int row0 = rowp * 128, col0 = colb * 64;

    const unsigned short* Wh = Wth + (size_t)z * (HD * NFE);
    const unsigned short* Wl_ = Wtl + (size_t)z * (HD * NFE);
    const float* bias = z ? br : bl;
    float* out = z ? outr : outl;

    int tid = threadIdx.x;
    int w = tid >> 6, lane = tid & 63;
    int wr0 = (w >> 1) * 64, wn0 = (w & 1) * 32;

    // staging roles: waves 0,2 -> A-hi ; 1,3 -> A-lo ; 0,1 -> B-hi ; 2,3 -> B-lo
    const unsigned short* asrc = (w & 1) ? xl : xh;
    short* adst = (w & 1) ? Al : Ah;
    int tb = (w >> 1) * 4;
    const unsigned short* bsrc = (w < 2) ? Wh : Wl_;
    short* bdst = (w < 2) ? Bh : Blo;
    int btb = (w & 1) * 2;

    f32x4 acc[4][2] = {};
    int kb_l = lane >> 4, r16 = lane & 15;

    for (int k0 = 0; k0 < NFE; k0 += 32) {
        #pragma unroll
        for (int t = 0; t < 4; ++t) {
            int tt = tb + t;
            int kb = tt >> 1, rr = (tt & 1) * 64 + lane;
            const unsigned short* g = asrc + (size_t)(row0 + rr) * NFE + k0 + kb * 8;
            __builtin_amdgcn_global_load_lds((const AS1 void*)g,
                                             (AS3 void*)(adst + tt * 512), 16, 0, 0);
        }
        #pragma unroll
        for (int t = 0; t < 2; ++t) {
            int tt = btb + t;
            const unsigned short* g = bsrc + (size_t)(col0 + lane) * NFE + k0 + tt * 8;
            __builtin_amdgcn_global_load_lds((const AS1 void*)g,
                                             (AS3 void*)(bdst + tt * 512), 16, 0, 0);
        }
        __syncthreads();

        short8 ah[4], al[4], bh[2], blv[2];
        #pragma unroll
        for (int mi = 0; mi < 4; ++mi) {
            int idx = (kb_l * 128 + wr0 + mi * 16 + r16) * 8;
            ah[mi] = *reinterpret_cast<const short8*>(&Ah[idx]);
            al[mi] = *reinterpret_cast<const short8*>(&Al[idx]);
        }
        #pragma unroll
        for (int ni = 0; ni < 2; ++ni) {
            int idx = (kb_l * 64 + wn0 + ni * 16 + r16) * 8;
            bh[ni]  = *reinterpret_cast<const short8*>(&Bh[idx]);
            blv[ni] = *reinterpret_cast<const short8*>(&Blo[idx]);
        }
        #pragma unroll
        for (int mi = 0; mi < 4; ++mi)
            #pragma unroll
            for (int ni = 0; ni < 2; ++ni) {
                acc[mi][ni] = __builtin_amdgcn_mfma_f32_16x16x32_bf16(ah[mi], bh[ni],  acc[mi][ni], 0, 0, 0);
                acc[mi][ni] = __builtin_amdgcn_mfma_f32_16x16x32_bf16(ah[mi], blv[ni], acc[mi][ni], 0, 0, 0);
                acc[mi][ni] = __builtin_amdgcn_mfma_f32_16x16x32_bf16(al[mi], bh[ni],  acc[mi][ni], 0, 0, 0);
            }
        __syncthreads();
    }

    int orow_base = row0 + wr0 + (lane >> 4) * 4;
    int ocol_base = col0 + wn0 + r16;
    #pragma unroll
    for (int mi = 0; mi < 4; ++mi)
        #pragma unroll
        for (int ni = 0; ni < 2; ++ni) {
            int col = ocol_base + ni * 16;
            float bv = bias[col];
            #pragma unroll
            for (int r = 0; r < 4; ++r) {
                int row = orow_base + mi * 16 + r;
                if (row < N_NODES)
                    out[(size_t)row * HD + col] = acc[mi][ni][r] + bv;
            }
        }
}

// ---------------- fused layer1 ----------------
__global__ __launch_bounds__(256) void fused1(const int* __restrict__ offs,
        const int* __restrict__ esrc,
        const float* __restrict__ xl1, const float* __restrict__ xr1,
        const float* __restrict__ att1, const float* __restrict__ bias1,
        float* __restrict__ hout) {
    int wid = (blockIdx.x * 256 + threadIdx.x) >> 6;
    int lane = threadIdx.x & 63;
    if (wid >= N_NODES) return;
    int beg = offs[wid], end = offs[wid + 1];

    float att[8], xr[8];
    *reinterpret_cast<float4*>(&att[0]) = *reinterpret_cast<const float4*>(att1 + lane * 8);
    *reinterpret_cast<float4*>(&att[4]) = *reinterpret_cast<const float4*>(att1 + lane * 8 + 4);
    const float* xrp = xr1 + (size_t)wid * HD + lane * 8;
    *reinterpret_cast<float4*>(&xr[0]) = *reinterpret_cast<const float4*>(xrp);
    *reinterpret_cast<float4*>(&xr[4]) = *reinterpret_cast<const float4*>(xrp + 4);

    float m = -3.4e38f, s = 0.f;
    float acc[8] = {};

    float xs[8];
    {
        int src = esrc[beg];
        const float* xp = xl1 + (size_t)src * HD + lane * 8;
        *reinterpret_cast<float4*>(&xs[0]) = *reinterpret_cast<const float4*>(xp);
        *reinterpret_cast<float4*>(&xs[4]) = *reinterpret_cast<const float4*>(xp + 4);
    }

    for (int j = beg; j < end; ++j) {
        float cx[8];
        #pragma unroll
        for (int q = 0; q < 8; ++q) cx[q] = xs[q];
        if (j + 1 < end) {
            int ns = esrc[j + 1];
            const float* np = xl1 + (size_t)ns * HD + lane * 8;
            *reinterpret_cast<float4*>(&xs[0]) = *reinterpret_cast<const float4*>(np);
            *reinterpret_cast<float4*>(&xs[4]) = *reinterpret_cast<const float4*>(np + 4);
        }
        float v = 0.f;
        #pragma unroll
        for (int q = 0; q < 8; ++q) {
            float t = cx[q] + xr[q];
            t = t > 0.f ? t : 0.2f * t;
            v = fmaf(t, att[q], v);
        }
        v += __shfl_xor(v, 1);
        v += __shfl_xor(v, 2);
        v += __shfl_xor(v, 4);
        float nm = fmaxf(m, v);
        float sc = __expf(m - nm);
        float p  = __expf(v - nm);
        s = s * sc + p;
        #pragma unroll
        for (int q = 0; q < 8; ++q) acc[q] = fmaf(acc[q], sc, p * cx[q]);
        m = nm;
    }

    float inv = 1.0f / s;
    float o[8];
    #pragma unroll
    for (int q = 0; q < 8; ++q) {
        float bi = bias1[lane * 8 + q];
        o[q] = fmaxf(fmaf(acc[q], inv, bi), 0.f);
    }
    float* op = hout + (size_t)wid * HD + lane * 8;
    *reinterpret_cast<float4*>(op)     = *reinterpret_cast<float4*>(&o[0]);
    *reinterpret_cast<float4*>(op + 4) = *reinterpret_cast<float4*>(&o[4]);
}

// ---------------- GEMM2: [20000x512] @ [512x16] x2 ----------------
__global__ __launch_bounds__(256) void gemm2(const float* __restrict__ h,
        const float* __restrict__ Wl2, const float* __restrict__ bl2,
        const float* __restrict__ Wr2, const float* __restrict__ br2,
        float* __restrict__ xl2, float* __restrict__ xr2) {
    int tx = threadIdx.x % 32;
    int ty = threadIdx.x / 32;
    int row = blockIdx.x * 8 + ty;
    if (row >= N_NODES) return;
    const float* W = (tx < 16) ? Wl2 : Wr2;
    int c = tx & 15;
    const float4* hr4 = reinterpret_cast<const float4*>(h + (size_t)row * HD);
    float acc = 0.f;
    #pragma unroll 4
    for (int k4 = 0; k4 < HD / 4; ++k4) {
        float4 v = hr4[k4];
        int k = k4 * 4;
        acc = fmaf(v.x, W[(k + 0) * NC + c], acc);
        acc = fmaf(v.y, W[(k + 1) * NC + c], acc);
        acc = fmaf(v.z, W[(k + 2) * NC + c], acc);
        acc = fmaf(v.w, W[(k + 3) * NC + c], acc);
    }
    if (tx < 16) xl2[(size_t)row * NC + c] = acc + bl2[c];
    else         xr2[(size_t)row * NC + c] = acc + br2[c];
}

// ---------------- fused layer2 ----------------
__global__ __launch_bounds__(256) void fused2(const int* __restrict__ offs,
        const int* __restrict__ esrc,
        const float* __restrict__ xl2, const float* __restrict__ xr2,
        const float* __restrict__ att2, const float* __restrict__ bias2,
        float* __restrict__ out) {
    int wid = (blockIdx.x * 256 + threadIdx.x) >> 6;
    int lane = threadIdx.x & 63;
    if (wid >= N_NODES) return;
    int g = lane >> 4, d = lane & 15;
    int beg = offs[wid], end = offs[wid + 1];

    float xr = xr2[(size_t)wid * NC + d];
    float at = att2[d];
    float m = -3.4e38f, s = 0.f, acc = 0.f;

    for (int j = beg + g; j < end; j += 4) {
        int src = esrc[j];
        float xs = xl2[(size_t)src * NC + d];
        float t = xs + xr;
        t = t > 0.f ? t : 0.2f * t;
        float v = t * at;
        v += __shfl_xor(v, 1);
        v += __shfl_xor(v, 2);
        v += __shfl_xor(v, 4);
        v += __shfl_xor(v, 8);
        float nm = fmaxf(m, v);
        float sc = __expf(m - nm), p = __expf(v - nm);
        s = s * sc + p;
        acc = fmaf(acc, sc, p * xs);
        m = nm;
    }
    #pragma unroll
    for (int off = 16; off < 64; off <<= 1) {
        float om = __shfl_xor(m, off);
        float os = __shfl_xor(s, off);
        float oa = __shfl_xor(acc, off);
        float nm = fmaxf(m, om);
        float c1 = __expf(m - nm), c2 = __expf(om - nm);
        s = s * c1 + os * c2;
        acc = acc * c1 + oa * c2;
        m = nm;
    }
    if (lane < 16) out[(size_t)wid * NC + d] = acc / s + bias2[d];
}

// ---------------- launch ----------------
extern "C" void kernel_launch(void* const* d_in, const int* in_sizes, int n_in,
                              void* d_out, int out_size, void* d_ws, size_t ws_size,
                              hipStream_t stream) {
    const float* x     = (const float*)d_in[0];
    const int*   ei    = (const int*)d_in[1];
    const float* W_l1  = (const float*)d_in[2];
    const float* b_l1  = (const float*)d_in[3];
    const float* W_r1  = (const float*)d_in[4];
    const float* b_r1  = (const float*)d_in[5];
    const float* att1  = (const float*)d_in[6];
    const float* bias1 = (const float*)d_in[7];
    const float* W_l2  = (const float*)d_in[8];
    const float* b_l2  = (const float*)d_in[9];
    const float* W_r2  = (const float*)d_in[10];
    const float* b_r2  = (const float*)d_in[11];
    const float* att2  = (const float*)d_in[12];
    const float* bias2 = (const float*)d_in[13];
    float* out = (float*)d_out;

    char* ws = (char*)d_ws;
    float* xl1  = (float*)ws; ws += (size_t)N_NODES * HD * sizeof(float);
    float* xr1  = (float*)ws; ws += (size_t)N_NODES * HD * sizeof(float);
    float* hbuf = (float*)ws; ws += (size_t)N_NODES * HD * sizeof(float);
    float* xl2  = (float*)ws; ws += (size_t)N_NODES * NC * sizeof(float);
    float* xr2  = (float*)ws; ws += (size_t)N_NODES * NC * sizeof(float);
    int* deg    = (int*)ws; ws += (size_t)N_NODES * sizeof(int);
    int* offs   = (int*)ws; ws += (size_t)(N_NODES + 1) * sizeof(int);
    int* cursor = (int*)ws; ws += (size_t)N_NODES * sizeof(int);
    int* esrc   = (int*)ws; ws += (size_t)ET * sizeof(int);
    unsigned short* xh  = (unsigned short*)ws; ws += (size_t)MPAD * NFE * sizeof(short);
    unsigned short* xlo = (unsigned short*)ws; ws += (size_t)MPAD * NFE * sizeof(short);
    unsigned short* Wth = (unsigned short*)ws; ws += (size_t)2 * HD * NFE * sizeof(short);
    unsigned short* Wtl = (unsigned short*)ws; ws += (size_t)2 * HD * NFE * sizeof(short);

    hipMemsetAsync(deg, 0, N_NODES * sizeof(int), stream);
    count_deg<<<(ET + 255) / 256, 256, 0, stream>>>(ei, deg);
    scan_offsets<<<1, 1024, 0, stream>>>(deg, offs, cursor);
    fill_csr<<<(ET + 255) / 256, 256, 0, stream>>>(ei, cursor, esrc);

    split_x<<<(N_NODES * NFE / 4 + 255) / 256, 256, 0, stream>>>(x, xh, xlo);
    split_w<<<dim3((NFE * HD + 255) / 256, 2), 256, 0, stream>>>(W_l1, W_r1, Wth, Wtl);

    gemm1m<<<G1_NWG, 256, 0, stream>>>(xh, xlo, Wth, Wtl, b_l1, b_r1, xl1, xr1);
    fused1<<<(N_NODES + 3) / 4, 256, 0, stream>>>(offs, esrc, xl1, xr1, att1, bias1, hbuf);

    gemm2<<<(N_NODES + 7) / 8, 256, 0, stream>>>(hbuf, W_l2, b_l2, W_r2, b_r2, xl2, xr2);
    fused2<<<(N_NODES + 3) / 4, 256, 0, stream>>>(offs, esrc, xl2, xr2, att2, bias2, out);
}

// Round 5
// 389.342 us; speedup vs baseline: 1.8707x; 1.1054x over previous
//
#include <hip/hip_runtime.h>
#include <hip/hip_bf16.h>
#include <stdint.h>

#define N_NODES 20000
#define MPAD    20096               // 157 * 128 padded rows for MFMA panels
#define N_EDG   320000
#define ET      (N_EDG + N_NODES)   // 340000
#define NFE     256
#define HD      512
#define NH      8
#define DH      64
#define NC      16

typedef __attribute__((ext_vector_type(8))) short short8;
typedef __attribute__((ext_vector_type(8))) _Float16 half8;
typedef __attribute__((ext_vector_type(4))) float f32x4;

#define AS1 __attribute__((address_space(1)))
#define AS3 __attribute__((address_space(3)))

__device__ __forceinline__ unsigned short f2bf(float f) {
    unsigned u = __float_as_uint(f);
    return (unsigned short)((u + 0x7FFFu + ((u >> 16) & 1u)) >> 16);
}
__device__ __forceinline__ float bf2f(unsigned short s) {
    return __uint_as_float(((unsigned)s) << 16);
}

// ---------------- CSR build ----------------
__global__ void count_deg(const int* __restrict__ ei, int* __restrict__ deg) {
    int e = blockIdx.x * 256 + threadIdx.x;
    if (e >= ET) return;
    int dst = (e < N_EDG) ? ei[N_EDG + e] : (e - N_EDG);
    atomicAdd(&deg[dst], 1);
}

__global__ __launch_bounds__(1024) void scan_offsets(const int* __restrict__ deg,
                                                     int* __restrict__ offs,
                                                     int* __restrict__ cur) {
    __shared__ int wsum[16];
    __shared__ int carry_s;
    int t = threadIdx.x;
    int wid = t >> 6, lane = t & 63;
    if (t == 0) { carry_s = 0; offs[0] = 0; }
    __syncthreads();
    for (int base = 0; base < N_NODES; base += 1024) {
        int i = base + t;
        int v = (i < N_NODES) ? deg[i] : 0;
        int sv = v;
        #pragma unroll
        for (int off = 1; off < 64; off <<= 1) {
            int n = __shfl_up(sv, off);
            if (lane >= off) sv += n;
        }
        if (lane == 63) wsum[wid] = sv;
        __syncthreads();
        int wpre = 0;
        #pragma unroll
        for (int w = 0; w < 16; ++w) wpre += (w < wid) ? wsum[w] : 0;
        int incl = sv + wpre + carry_s;
        if (i < N_NODES) {
            offs[i + 1] = incl;
            cur[i] = incl - v;
        }
        __syncthreads();
        if (t == 1023) carry_s = incl;
        __syncthreads();
    }
}

__global__ void fill_csr(const int* __restrict__ ei, int* __restrict__ cur,
                         int* __restrict__ esrc) {
    int e = blockIdx.x * 256 + threadIdx.x;
    if (e >= ET) return;
    int src, dst;
    if (e < N_EDG) { src = ei[e]; dst = ei[N_EDG + e]; }
    else { src = e - N_EDG; dst = src; }
    int pos = atomicAdd(&cur[dst], 1);
    esrc[pos] = src;
}

// ---------------- split fp32 -> bf16 hi/lo ----------------
__global__ __launch_bounds__(256) void split_x(const float* __restrict__ x,
        unsigned short* __restrict__ xh, unsigned short* __restrict__ xl) {
    int i = (blockIdx.x * 256 + threadIdx.x) * 4;
    if (i >= N_NODES * NFE) return;
    float4 v = *reinterpret_cast<const float4*>(x + i);
    ushort4 h, l;
    h.x = f2bf(v.x); l.x = f2bf(v.x - bf2f(h.x));
    h.y = f2bf(v.y); l.y = f2bf(v.y - bf2f(h.y));
    h.z = f2bf(v.z); l.z = f2bf(v.z - bf2f(h.z));
    h.w = f2bf(v.w); l.w = f2bf(v.w - bf2f(h.w));
    *reinterpret_cast<ushort4*>(xh + i) = h;
    *reinterpret_cast<ushort4*>(xl + i) = l;
}

// split + transpose W [256x512] -> Wt [512][256] (k contiguous), both matrices
__global__ __launch_bounds__(256) void split_w(const float* __restrict__ Wl,
        const float* __restrict__ Wr, unsigned short* __restrict__ Wth,
        unsigned short* __restrict__ Wtl) {
    const float* W = blockIdx.y ? Wr : Wl;
    unsigned short* oh = Wth + (size_t)blockIdx.y * (HD * NFE);
    unsigned short* ol = Wtl + (size_t)blockIdx.y * (HD * NFE);
    int i = blockIdx.x * 256 + threadIdx.x;
    if (i >= NFE * HD) return;
    int k = i >> 9, n = i & 511;
    float v = W[i];
    unsigned short h = f2bf(v), l = f2bf(v - bf2f(h));
    oh[n * NFE + k] = h;
    ol[n * NFE + k] = l;
}

// ---------------- GEMM1 via split-bf16 MFMA, fp16 output ----------------
#define ROWP 157
#define G1_NWG (8 * ROWP * 2)   // 2512; /8 = 314 exactly -> bijective swizzle
__global__ __launch_bounds__(256) void gemm1m(
        const unsigned short* __restrict__ xh, const unsigned short* __restrict__ xl,
        const unsigned short* __restrict__ Wth, const unsigned short* __restrict__ Wtl,
        const float* __restrict__ bl, const float* __restrict__ br,
        _Float16* __restrict__ outl, _Float16* __restrict__ outr) {
    __shared__ short Ah[4 * 128 * 8], Al[4 * 128 * 8];   // [kb][row][8]
    __shared__ short Bh[4 * 64 * 8],  Blo[4 * 64 * 8];   // [kb][n][8]

    int flat = blockIdx.x;
    int wgid = (flat & 7) * (G1_NWG / 8) + (flat >> 3);
    int z = wgid / (8 * ROWP);
    int rem = wgid - z * (8 * ROWP);
    int rowp = rem >> 3, colb = rem & 7;
    int row0 = rowp * 128, col0 = colb * 64;

    const unsigned short* Wh = Wth + (size_t)z * (HD * NFE);
    const unsigned short* Wl_ = Wtl + (size_t)z * (HD * NFE);
    const float* bias = z ? br : bl;
    _Float16* out = z ? outr : outl;

    int tid = threadIdx.x;
    int w = tid >> 6, lane = tid & 63;
    int wr0 = (w >> 1) * 64, wn0 = (w & 1) * 32;

    const unsigned short* asrc = (w & 1) ? xl : xh;
    short* adst = (w & 1) ? Al : Ah;
    int tb = (w >> 1) * 4;
    const unsigned short* bsrc = (w < 2) ? Wh : Wl_;
    short* bdst = (w < 2) ? Bh : Blo;
    int btb = (w & 1) * 2;

    f32x4 acc[4][2] = {};
    int kb_l = lane >> 4, r16 = lane & 15;

    for (int k0 = 0; k0 < NFE; k0 += 32) {
        #pragma unroll
        for (int t = 0; t < 4; ++t) {
            int tt = tb + t;
            int kb = tt >> 1, rr = (tt & 1) * 64 + lane;
            const unsigned short* g = asrc + (size_t)(row0 + rr) * NFE + k0 + kb * 8;
            __builtin_amdgcn_global_load_lds((const AS1 void*)g,
                                             (AS3 void*)(adst + tt * 512), 16, 0, 0);
        }
        #pragma unroll
        for (int t = 0; t < 2; ++t) {
            int tt = btb + t;
            const unsigned short* g = bsrc + (size_t)(col0 + lane) * NFE + k0 + tt * 8;
            __builtin_amdgcn_global_load_lds((const AS1 void*)g,
                                             (AS3 void*)(bdst + tt * 512), 16, 0, 0);
        }
        __syncthreads();

        short8 ah[4], al[4], bh[2], blv[2];
        #pragma unroll
        for (int mi = 0; mi < 4; ++mi) {
            int idx = (kb_l * 128 + wr0 + mi * 16 + r16) * 8;
            ah[mi] = *reinterpret_cast<const short8*>(&Ah[idx]);
            al[mi] = *reinterpret_cast<const short8*>(&Al[idx]);
        }
        #pragma unroll
        for (int ni = 0; ni < 2; ++ni) {
            int idx = (kb_l * 64 + wn0 + ni * 16 + r16) * 8;
            bh[ni]  = *reinterpret_cast<const short8*>(&Bh[idx]);
            blv[ni] = *reinterpret_cast<const short8*>(&Blo[idx]);
        }
        #pragma unroll
        for (int mi = 0; mi < 4; ++mi)
            #pragma unroll
            for (int ni = 0; ni < 2; ++ni) {
                acc[mi][ni] = __builtin_amdgcn_mfma_f32_16x16x32_bf16(ah[mi], bh[ni],  acc[mi][ni], 0, 0, 0);
                acc[mi][ni] = __builtin_amdgcn_mfma_f32_16x16x32_bf16(ah[mi], blv[ni], acc[mi][ni], 0, 0, 0);
                acc[mi][ni] = __builtin_amdgcn_mfma_f32_16x16x32_bf16(al[mi], bh[ni],  acc[mi][ni], 0, 0, 0);
            }
        __syncthreads();
    }

    int orow_base = row0 + wr0 + (lane >> 4) * 4;
    int ocol_base = col0 + wn0 + r16;
    #pragma unroll
    for (int mi = 0; mi < 4; ++mi)
        #pragma unroll
        for (int ni = 0; ni < 2; ++ni) {
            int col = ocol_base + ni * 16;
            float bv = bias[col];
            #pragma unroll
            for (int r = 0; r < 4; ++r) {
                int row = orow_base + mi * 16 + r;
                if (row < N_NODES)
                    out[(size_t)row * HD + col] = (_Float16)(acc[mi][ni][r] + bv);
            }
        }
}

// ---------------- fused layer1: fp16 gather, fp32 compute ----------------
__global__ __launch_bounds__(256) void fused1(const int* __restrict__ offs,
        const int* __restrict__ esrc,
        const _Float16* __restrict__ xl1, const _Float16* __restrict__ xr1,
        const float* __restrict__ att1, const float* __restrict__ bias1,
        float* __restrict__ hout) {
    int wid = (blockIdx.x * 256 + threadIdx.x) >> 6;
    int lane = threadIdx.x & 63;
    if (wid >= N_NODES) return;
    int beg = offs[wid], end = offs[wid + 1];

    float att[8], xr[8];
    *reinterpret_cast<float4*>(&att[0]) = *reinterpret_cast<const float4*>(att1 + lane * 8);
    *reinterpret_cast<float4*>(&att[4]) = *reinterpret_cast<const float4*>(att1 + lane * 8 + 4);
    {
        half8 hv = *reinterpret_cast<const half8*>(xr1 + (size_t)wid * HD + lane * 8);
        #pragma unroll
        for (int q = 0; q < 8; ++q) xr[q] = (float)hv[q];
    }

    float m = -3.4e38f, s = 0.f;
    float acc[8] = {};

    half8 xsp;   // prefetched raw fp16 row fragment (16 B, one load)
    xsp = *reinterpret_cast<const half8*>(xl1 + (size_t)esrc[beg] * HD + lane * 8);

    for (int j = beg; j < end; ++j) {
        half8 curh = xsp;
        if (j + 1 < end)
            xsp = *reinterpret_cast<const half8*>(xl1 + (size_t)esrc[j + 1] * HD + lane * 8);
        float cx[8];
        #pragma unroll
        for (int q = 0; q < 8; ++q) cx[q] = (float)curh[q];

        float v = 0.f;
        #pragma unroll
        for (int q = 0; q < 8; ++q) {
            float t = cx[q] + xr[q];
            t = t > 0.f ? t : 0.2f * t;
            v = fmaf(t, att[q], v);
        }
        v += __shfl_xor(v, 1);
        v += __shfl_xor(v, 2);
        v += __shfl_xor(v, 4);
        float nm = fmaxf(m, v);
        float sc = __expf(m - nm);
        float p  = __expf(v - nm);
        s = s * sc + p;
        #pragma unroll
        for (int q = 0; q < 8; ++q) acc[q] = fmaf(acc[q], sc, p * cx[q]);
        m = nm;
    }

    float inv = 1.0f / s;
    float o[8];
    #pragma unroll
    for (int q = 0; q < 8; ++q) {
        float bi = bias1[lane * 8 + q];
        o[q] = fmaxf(fmaf(acc[q], inv, bi), 0.f);
    }
    float* op = hout + (size_t)wid * HD + lane * 8;
    *reinterpret_cast<float4*>(op)     = *reinterpret_cast<float4*>(&o[0]);
    *reinterpret_cast<float4*>(op + 4) = *reinterpret_cast<float4*>(&o[4]);
}

// ---------------- GEMM2: [20000x512] @ [512x16] x2 ----------------
__global__ __launch_bounds__(256) void gemm2(const float* __restrict__ h,
        const float* __restrict__ Wl2, const float* __restrict__ bl2,
        const float* __restrict__ Wr2, const float* __restrict__ br2,
        float* __restrict__ xl2, float* __restrict__ xr2) {
    int tx = threadIdx.x % 32;
    int ty = threadIdx.x / 32;
    int row = blockIdx.x * 8 + ty;
    if (row >= N_NODES) return;
    const float* W = (tx < 16) ? Wl2 : Wr2;
    int c = tx & 15;
    const float4* hr4 = reinterpret_cast<const float4*>(h + (size_t)row * HD);
    float acc = 0.f;
    #pragma unroll 4
    for (int k4 = 0; k4 < HD / 4; ++k4) {
        float4 v = hr4[k4];
        int k = k4 * 4;
        acc = fmaf(v.x, W[(k + 0) * NC + c], acc);
        acc = fmaf(v.y, W[(k + 1) * NC + c], acc);
        acc = fmaf(v.z, W[(k + 2) * NC + c], acc);
        acc = fmaf(v.w, W[(k + 3) * NC + c], acc);
    }
    if (tx < 16) xl2[(size_t)row * NC + c] = acc + bl2[c];
    else         xr2[(size_t)row * NC + c] = acc + br2[c];
}

// ---------------- fused layer2 ----------------
__global__ __launch_bounds__(256) void fused2(const int* __restrict__ offs,
        const int* __restrict__ esrc,
        const float* __restrict__ xl2, const float* __restrict__ xr2,
        const float* __restrict__ att2, const float* __restrict__ bias2,
        float* __restrict__ out) {
    int wid = (blockIdx.x * 256 + threadIdx.x) >> 6;
    int lane = threadIdx.x & 63;
    if (wid >= N_NODES) return;
    int g = lane >> 4, d = lane & 15;
    int beg = offs[wid], end = offs[wid + 1];

    float xr = xr2[(size_t)wid * NC + d];
    float at = att2[d];
    float m = -3.4e38f, s = 0.f, acc = 0.f;

    for (int j = beg + g; j < end; j += 4) {
        int src = esrc[j];
        float xs = xl2[(size_t)src * NC + d];
        float t = xs + xr;
        t = t > 0.f ? t : 0.2f * t;
        float v = t * at;
        v += __shfl_xor(v, 1);
        v += __shfl_xor(v, 2);
        v += __shfl_xor(v, 4);
        v += __shfl_xor(v, 8);
        float nm = fmaxf(m, v);
        float sc = __expf(m - nm), p = __expf(v - nm);
        s = s * sc + p;
        acc = fmaf(acc, sc, p * xs);
        m = nm;
    }
    #pragma unroll
    for (int off = 16; off < 64; off <<= 1) {
        float om = __shfl_xor(m, off);
        float os = __shfl_xor(s, off);
        float oa = __shfl_xor(acc, off);
        float nm = fmaxf(m, om);
        float c1 = __expf(m - nm), c2 = __expf(om - nm);
        s = s * c1 + os * c2;
        acc = acc * c1 + oa * c2;
        m = nm;
    }
    if (lane < 16) out[(size_t)wid * NC + d] = acc / s + bias2[d];
}

// ---------------- launch ----------------
extern "C" void kernel_launch(void* const* d_in, const int* in_sizes, int n_in,
                              void* d_out, int out_size, void* d_ws, size_t ws_size,
                              hipStream_t stream) {
    const float* x     = (const float*)d_in[0];
    const int*   ei    = (const int*)d_in[1];
    const float* W_l1  = (const float*)d_in[2];
    const float* b_l1  = (const float*)d_in[3];
    const float* W_r1  = (const float*)d_in[4];
    const float* b_r1  = (const float*)d_in[5];
    const float* att1  = (const float*)d_in[6];
    const float* bias1 = (const float*)d_in[7];
    const float* W_l2  = (const float*)d_in[8];
    const float* b_l2  = (const float*)d_in[9];
    const float* W_r2  = (const float*)d_in[10];
    const float* b_r2  = (const float*)d_in[11];
    const float* att2  = (const float*)d_in[12];
    const float* bias2 = (const float*)d_in[13];
    float* out = (float*)d_out;

    char* ws = (char*)d_ws;
    _Float16* xl1 = (_Float16*)ws; ws += (size_t)N_NODES * HD * sizeof(_Float16);
    _Float16* xr1 = (_Float16*)ws; ws += (size_t)N_NODES * HD * sizeof(_Float16);
    float* hbuf = (float*)ws; ws += (size_t)N_NODES * HD * sizeof(float);
    float* xl2  = (float*)ws; ws += (size_t)N_NODES * NC * sizeof(float);
    float* xr2  = (float*)ws; ws += (size_t)N_NODES * NC * sizeof(float);
    int* deg    = (int*)ws; ws += (size_t)N_NODES * sizeof(int);
    int* offs   = (int*)ws; ws += (size_t)(N_NODES + 1) * sizeof(int);
    int* cursor = (int*)ws; ws += (size_t)N_NODES * sizeof(int);
    int* esrc   = (int*)ws; ws += (size_t)ET * sizeof(int);
    unsigned short* xh  = (unsigned short*)ws; ws += (size_t)MPAD * NFE * sizeof(short);
    unsigned short* xlo = (unsigned short*)ws; ws += (size_t)MPAD * NFE * sizeof(short);
    unsigned short* Wth = (unsigned short*)ws; ws += (size_t)2 * HD * NFE * sizeof(short);
    unsigned short* Wtl = (unsigned short*)ws; ws += (size_t)2 * HD * NFE * sizeof(short);

    hipMemsetAsync(deg, 0, N_NODES * sizeof(int), stream);
    count_deg<<<(ET + 255) / 256, 256, 0, stream>>>(ei, deg);
    scan_offsets<<<1, 1024, 0, stream>>>(deg, offs, cursor);
    fill_csr<<<(ET + 255) / 256, 256, 0, stream>>>(ei, cursor, esrc);

    split_x<<<(N_NODES * NFE / 4 + 255) / 256, 256, 0, stream>>>(x, xh, xlo);
    split_w<<<dim3((NFE * HD + 255) / 256, 2), 256, 0, stream>>>(W_l1, W_r1, Wth, Wtl);

    gemm1m<<<G1_NWG, 256, 0, stream>>>(xh, xlo, Wth, Wtl, b_l1, b_r1, xl1, xr1);
    fused1<<<(N_NODES + 3) / 4, 256, 0, stream>>>(offs, esrc, xl1, xr1, att1, bias1, hbuf);

    gemm2<<<(N_NODES + 7) / 8, 256, 0, stream>>>(hbuf, W_l2, b_l2, W_r2, b_r2, xl2, xr2);
    fused2<<<(N_NODES + 3) / 4, 256, 0, stream>>>(offs, esrc, xl2, xr2, att2, bias2, out);
}

// Round 6
// 366.247 us; speedup vs baseline: 1.9887x; 1.0631x over previous
//
#include <hip/hip_runtime.h>
#include <hip/hip_bf16.h>
#include <stdint.h>

#define N_NODES 20000
#define MPAD    20096               // 157 * 128 padded rows for MFMA panels
#define N_EDG   320000
#define ET      (N_EDG + N_NODES)   // 340000
#define NFE     256
#define HD      512
#define NH      8
#define DH      64
#define NC      16

typedef __attribute__((ext_vector_type(8))) short short8;
typedef __attribute__((ext_vector_type(8))) _Float16 half8;
typedef __attribute__((ext_vector_type(4))) float f32x4;

#define AS1 __attribute__((address_space(1)))
#define AS3 __attribute__((address_space(3)))

__device__ __forceinline__ unsigned short f2bf(float f) {
    unsigned u = __float_as_uint(f);
    return (unsigned short)((u + 0x7FFFu + ((u >> 16) & 1u)) >> 16);
}
__device__ __forceinline__ float bf2f(unsigned short s) {
    return __uint_as_float(((unsigned)s) << 16);
}

// ---------------- CSR build ----------------
__global__ void count_deg(const int* __restrict__ ei, int* __restrict__ deg) {
    int e = blockIdx.x * 256 + threadIdx.x;
    if (e >= ET) return;
    int dst = (e < N_EDG) ? ei[N_EDG + e] : (e - N_EDG);
    atomicAdd(&deg[dst], 1);
}

__global__ __launch_bounds__(1024) void scan_offsets(const int* __restrict__ deg,
                                                     int* __restrict__ offs,
                                                     int* __restrict__ cur) {
    __shared__ int wsum[16];
    __shared__ int carry_s;
    int t = threadIdx.x;
    int wid = t >> 6, lane = t & 63;
    if (t == 0) { carry_s = 0; offs[0] = 0; }
    __syncthreads();
    for (int base = 0; base < N_NODES; base += 1024) {
        int i = base + t;
        int v = (i < N_NODES) ? deg[i] : 0;
        int sv = v;
        #pragma unroll
        for (int off = 1; off < 64; off <<= 1) {
            int n = __shfl_up(sv, off);
            if (lane >= off) sv += n;
        }
        if (lane == 63) wsum[wid] = sv;
        __syncthreads();
        int wpre = 0;
        #pragma unroll
        for (int w = 0; w < 16; ++w) wpre += (w < wid) ? wsum[w] : 0;
        int incl = sv + wpre + carry_s;
        if (i < N_NODES) {
            offs[i + 1] = incl;
            cur[i] = incl - v;
        }
        __syncthreads();
        if (t == 1023) carry_s = incl;
        __syncthreads();
    }
}

__global__ void fill_csr(const int* __restrict__ ei, int* __restrict__ cur,
                         int* __restrict__ esrc) {
    int e = blockIdx.x * 256 + threadIdx.x;
    if (e >= ET) return;
    int src, dst;
    if (e < N_EDG) { src = ei[e]; dst = ei[N_EDG + e]; }
    else { src = e - N_EDG; dst = src; }
    int pos = atomicAdd(&cur[dst], 1);
    esrc[pos] = src;
}

// ---------------- split fp32 -> bf16 hi/lo ----------------
__global__ __launch_bounds__(256) void split_x(const float* __restrict__ x,
        unsigned short* __restrict__ xh, unsigned short* __restrict__ xl) {
    int i = (blockIdx.x * 256 + threadIdx.x) * 4;
    if (i >= N_NODES * NFE) return;
    float4 v = *reinterpret_cast<const float4*>(x + i);
    ushort4 h, l;
    h.x = f2bf(v.x); l.x = f2bf(v.x - bf2f(h.x));
    h.y = f2bf(v.y); l.y = f2bf(v.y - bf2f(h.y));
    h.z = f2bf(v.z); l.z = f2bf(v.z - bf2f(h.z));
    h.w = f2bf(v.w); l.w = f2bf(v.w - bf2f(h.w));
    *reinterpret_cast<ushort4*>(xh + i) = h;
    *reinterpret_cast<ushort4*>(xl + i) = l;
}

// split + transpose W [256x512] -> Wt [512][256] (k contiguous), both matrices
__global__ __launch_bounds__(256) void split_w(const float* __restrict__ Wl,
        const float* __restrict__ Wr, unsigned short* __restrict__ Wth,
        unsigned short* __restrict__ Wtl) {
    const float* W = blockIdx.y ? Wr : Wl;
    unsigned short* oh = Wth + (size_t)blockIdx.y * (HD * NFE);
    unsigned short* ol = Wtl + (size_t)blockIdx.y * (HD * NFE);
    int i = blockIdx.x * 256 + threadIdx.x;
    if (i >= NFE * HD) return;
    int k = i >> 9, n = i & 511;
    float v = W[i];
    unsigned short h = f2bf(v), l = f2bf(v - bf2f(h));
    oh[n * NFE + k] = h;
    ol[n * NFE + k] = l;
}

// ---------------- GEMM1 via split-bf16 MFMA, fp16 output ----------------
// Double-buffered 2-phase pipeline; coalesced global_load_lds (16 rows x 64B
// slice per instruction = 1024 contiguous LDS bytes, 16 L2 lines not 64).
// LDS layout: A[buf][row][32k] linear, B[buf][col][32k] linear.
#define ROWP 157
#define G1_NWG (8 * ROWP * 2)   // 2512; /8 = 314 exactly -> bijective swizzle
__global__ __launch_bounds__(256) void gemm1m(
        const unsigned short* __restrict__ xh, const unsigned short* __restrict__ xl,
        const unsigned short* __restrict__ Wth, const unsigned short* __restrict__ Wtl,
        const float* __restrict__ bl, const float* __restrict__ br,
        _Float16* __restrict__ outl, _Float16* __restrict__ outr) {
    __shared__ __align__(16) short Ah[2][128 * 32], Al[2][128 * 32];
    __shared__ __align__(16) short Bh[2][64 * 32],  Bls[2][64 * 32];

    int flat = blockIdx.x;
    int wgid = (flat & 7) * (G1_NWG / 8) + (flat >> 3);
    int z = wgid / (8 * ROWP);
    int rem = wgid - z * (8 * ROWP);
    int rowp = rem >> 3, colb = rem & 7;
    int row0 = rowp * 128, col0 = colb * 64;

    const unsigned short* Wh  = Wth + (size_t)z * (HD * NFE);
    const unsigned short* Wl_ = Wtl + (size_t)z * (HD * NFE);
    const float* bias = z ? br : bl;
    _Float16* out = z ? outr : outl;

    int tid = threadIdx.x;
    int w = tid >> 6, lane = tid & 63;
    int wr0 = (w >> 1) * 64, wn0 = (w & 1) * 32;
    int r16 = lane & 15, kb_l = lane >> 4;
    int rsub = lane >> 2, kch = lane & 3;   // staging roles

    f32x4 acc[4][2] = {};

    auto stage = [&](int buf, int k0) {
        #pragma unroll
        for (int i = 0; i < 2; ++i) {
            int inst = 2 * w + i;                 // 0..7
            int rl = inst * 16 + rsub;            // 0..127
            size_t goff = (size_t)(row0 + rl) * NFE + k0 + kch * 8;
            __builtin_amdgcn_global_load_lds((const AS1 void*)(xh + goff),
                                             (AS3 void*)(&Ah[buf][inst * 512]), 16, 0, 0);
            __builtin_amdgcn_global_load_lds((const AS1 void*)(xl + goff),
                                             (AS3 void*)(&Al[buf][inst * 512]), 16, 0, 0);
        }
        int cl = w * 16 + rsub;                   // 0..63
        size_t boff = (size_t)(col0 + cl) * NFE + k0 + kch * 8;
        __builtin_amdgcn_global_load_lds((const AS1 void*)(Wh + boff),
                                         (AS3 void*)(&Bh[buf][w * 512]), 16, 0, 0);
        __builtin_amdgcn_global_load_lds((const AS1 void*)(Wl_ + boff),
                                         (AS3 void*)(&Bls[buf][w * 512]), 16, 0, 0);
    };

    stage(0, 0);
    __syncthreads();

    for (int t = 0; t < 8; ++t) {
        int buf = t & 1;
        if (t < 7) stage(buf ^ 1, (t + 1) * 32);   // overlap with compute below

        short8 ah[4], alv[4], bhv[2], blv[2];
        #pragma unroll
        for (int mi = 0; mi < 4; ++mi) {
            int idx = (wr0 + mi * 16 + r16) * 32 + kb_l * 8;
            ah[mi]  = *reinterpret_cast<const short8*>(&Ah[buf][idx]);
            alv[mi] = *reinterpret_cast<const short8*>(&Al[buf][idx]);
        }
        #pragma unroll
        for (int ni = 0; ni < 2; ++ni) {
            int idx = (wn0 + ni * 16 + r16) * 32 + kb_l * 8;
            bhv[ni] = *reinterpret_cast<const short8*>(&Bh[buf][idx]);
            blv[ni] = *reinterpret_cast<const short8*>(&Bls[buf][idx]);
        }
        #pragma unroll
        for (int mi = 0; mi < 4; ++mi)
            #pragma unroll
            for (int ni = 0; ni < 2; ++ni) {
                acc[mi][ni] = __builtin_amdgcn_mfma_f32_16x16x32_bf16(ah[mi],  bhv[ni], acc[mi][ni], 0, 0, 0);
                acc[mi][ni] = __builtin_amdgcn_mfma_f32_16x16x32_bf16(ah[mi],  blv[ni], acc[mi][ni], 0, 0, 0);
                acc[mi][ni] = __builtin_amdgcn_mfma_f32_16x16x32_bf16(alv[mi], bhv[ni], acc[mi][ni], 0, 0, 0);
            }
        __syncthreads();   // drains next-tile staging (vmcnt0) + protects buf reuse
    }

    int orow_base = row0 + wr0 + kb_l * 4;
    int ocol_base = col0 + wn0 + r16;
    #pragma unroll
    for (int mi = 0; mi < 4; ++mi)
        #pragma unroll
        for (int ni = 0; ni < 2; ++ni) {
            int col = ocol_base + ni * 16;
            float bv = bias[col];
            #pragma unroll
            for (int r = 0; r < 4; ++r) {
                int row = orow_base + mi * 16 + r;
                if (row < N_NODES)
                    out[(size_t)row * HD + col] = (_Float16)(acc[mi][ni][r] + bv);
            }
        }
}

// ---------------- fused layer1: fp16 gather, fp32 compute ----------------
__global__ __launch_bounds__(256) void fused1(const int* __restrict__ offs,
        const int* __restrict__ esrc,
        const _Float16* __restrict__ xl1, const _Float16* __restrict__ xr1,
        const float* __restrict__ att1, const float* __restrict__ bias1,
        float* __restrict__ hout) {
    int wid = (blockIdx.x * 256 + threadIdx.x) >> 6;
    int lane = threadIdx.x & 63;
    if (wid >= N_NODES) return;
    int beg = offs[wid], end = offs[wid + 1];

    float att[8], xr[8];
    *reinterpret_cast<float4*>(&att[0]) = *reinterpret_cast<const float4*>(att1 + lane * 8);
    *reinterpret_cast<float4*>(&att[4]) = *reinterpret_cast<const float4*>(att1 + lane * 8 + 4);
    {
        half8 hv = *reinterpret_cast<const half8*>(xr1 + (size_t)wid * HD + lane * 8);
        #pragma unroll
        for (int q = 0; q < 8; ++q) xr[q] = (float)hv[q];
    }

    float m = -3.4e38f, s = 0.f;
    float acc[8] = {};

    half8 xsp;
    xsp = *reinterpret_cast<const half8*>(xl1 + (size_t)esrc[beg] * HD + lane * 8);

    for (int j = beg; j < end; ++j) {
        half8 curh = xsp;
        if (j + 1 < end)
            xsp = *reinterpret_cast<const half8*>(xl1 + (size_t)esrc[j + 1] * HD + lane * 8);
        float cx[8];
        #pragma unroll
        for (int q = 0; q < 8; ++q) cx[q] = (float)curh[q];

        float v = 0.f;
        #pragma unroll
        for (int q = 0; q < 8; ++q) {
            float t = cx[q] + xr[q];
            t = t > 0.f ? t : 0.2f * t;
            v = fmaf(t, att[q], v);
        }
        v += __shfl_xor(v, 1);
        v += __shfl_xor(v, 2);
        v += __shfl_xor(v, 4);
        float nm = fmaxf(m, v);
        float sc = __expf(m - nm);
        float p  = __expf(v - nm);
        s = s * sc + p;
        #pragma unroll
        for (int q = 0; q < 8; ++q) acc[q] = fmaf(acc[q], sc, p * cx[q]);
        m = nm;
    }

    float inv = 1.0f / s;
    float o[8];
    #pragma unroll
    for (int q = 0; q < 8; ++q) {
        float bi = bias1[lane * 8 + q];
        o[q] = fmaxf(fmaf(acc[q], inv, bi), 0.f);
    }
    float* op = hout + (size_t)wid * HD + lane * 8;
    *reinterpret_cast<float4*>(op)     = *reinterpret_cast<float4*>(&o[0]);
    *reinterpret_cast<float4*>(op + 4) = *reinterpret_cast<float4*>(&o[4]);
}

// ---------------- GEMM2: [20000x512] @ [512x16] x2 ----------------
__global__ __launch_bounds__(256) void gemm2(const float* __restrict__ h,
        const float* __restrict__ Wl2, const float* __restrict__ bl2,
        const float* __restrict__ Wr2, const float* __restrict__ br2,
        float* __restrict__ xl2, float* __restrict__ xr2) {
    int tx = threadIdx.x % 32;
    int ty = threadIdx.x / 32;
    int row = blockIdx.x * 8 + ty;
    if (row >= N_NODES) return;
    const float* W = (tx < 16) ? Wl2 : Wr2;
    int c = tx & 15;
    const float4* hr4 = reinterpret_cast<const float4*>(h + (size_t)row * HD);
    float acc = 0.f;
    #pragma unroll 4
    for (int k4 = 0; k4 < HD / 4; ++k4) {
        float4 v = hr4[k4];
        int k = k4 * 4;
        acc = fmaf(v.x, W[(k + 0) * NC + c], acc);
        acc = fmaf(v.y, W[(k + 1) * NC + c], acc);
        acc = fmaf(v.z, W[(k + 2) * NC + c], acc);
        acc = fmaf(v.w, W[(k + 3) * NC + c], acc);
    }
    if (tx < 16) xl2[(size_t)row * NC + c] = acc + bl2[c];
    else         xr2[(size_t)row * NC + c] = acc + br2[c];
}

// ---------------- fused layer2 ----------------
__global__ __launch_bounds__(256) void fused2(const int* __restrict__ offs,
        const int* __restrict__ esrc,
        const float* __restrict__ xl2, const float* __restrict__ xr2,
        const float* __restrict__ att2, const float* __restrict__ bias2,
        float* __restrict__ out) {
    int wid = (blockIdx.x * 256 + threadIdx.x) >> 6;
    int lane = threadIdx.x & 63;
    if (wid >= N_NODES) return;
    int g = lane >> 4, d = lane & 15;
    int beg = offs[wid], end = offs[wid + 1];

    float xr = xr2[(size_t)wid * NC + d];
    float at = att2[d];
    float m = -3.4e38f, s = 0.f, acc = 0.f;

    for (int j = beg + g; j < end; j += 4) {
        int src = esrc[j];
        float xs = xl2[(size_t)src * NC + d];
        float t = xs + xr;
        t = t > 0.f ? t : 0.2f * t;
        float v = t * at;
        v += __shfl_xor(v, 1);
        v += __shfl_xor(v, 2);
        v += __shfl_xor(v, 4);
        v += __shfl_xor(v, 8);
        float nm = fmaxf(m, v);
        float sc = __expf(m - nm), p = __expf(v - nm);
        s = s * sc + p;
        acc = fmaf(acc, sc, p * xs);
        m = nm;
    }
    #pragma unroll
    for (int off = 16; off < 64; off <<= 1) {
        float om = __shfl_xor(m, off);
        float os = __shfl_xor(s, off);
        float oa = __shfl_xor(acc, off);
        float nm = fmaxf(m, om);
        float c1 = __expf(m - nm), c2 = __expf(om - nm);
        s = s * c1 + os * c2;
        acc = acc * c1 + oa * c2;
        m = nm;
    }
    if (lane < 16) out[(size_t)wid * NC + d] = acc / s + bias2[d];
}

// ---------------- launch ----------------
extern "C" void kernel_launch(void* const* d_in, const int* in_sizes, int n_in,
                              void* d_out, int out_size, void* d_ws, size_t ws_size,
                              hipStream_t stream) {
    const float* x     = (const float*)d_in[0];
    const int*   ei    = (const int*)d_in[1];
    const float* W_l1  = (const float*)d_in[2];
    const float* b_l1  = (const float*)d_in[3];
    const float* W_r1  = (const float*)d_in[4];
    const float* b_r1  = (const float*)d_in[5];
    const float* att1  = (const float*)d_in[6];
    const float* bias1 = (const float*)d_in[7];
    const float* W_l2  = (const float*)d_in[8];
    const float* b_l2  = (const float*)d_in[9];
    const float* W_r2  = (const float*)d_in[10];
    const float* b_r2  = (const float*)d_in[11];
    const float* att2  = (const float*)d_in[12];
    const float* bias2 = (const float*)d_in[13];
    float* out = (float*)d_out;

    char* ws = (char*)d_ws;
    _Float16* xl1 = (_Float16*)ws; ws += (size_t)N_NODES * HD * sizeof(_Float16);
    _Float16* xr1 = (_Float16*)ws; ws += (size_t)N_NODES * HD * sizeof(_Float16);
    float* hbuf = (float*)ws; ws += (size_t)N_NODES * HD * sizeof(float);
    float* xl2  = (float*)ws; ws += (size_t)N_NODES * NC * sizeof(float);
    float* xr2  = (float*)ws; ws += (size_t)N_NODES * NC * sizeof(float);
    int* deg    = (int*)ws; ws += (size_t)N_NODES * sizeof(int);
    int* offs   = (int*)ws; ws += (size_t)(N_NODES + 1) * sizeof(int);
    int* cursor = (int*)ws; ws += (size_t)N_NODES * sizeof(int);
    int* esrc   = (int*)ws; ws += (size_t)ET * sizeof(int);
    unsigned short* xh  = (unsigned short*)ws; ws += (size_t)MPAD * NFE * sizeof(short);
    unsigned short* xlo = (unsigned short*)ws; ws += (size_t)MPAD * NFE * sizeof(short);
    unsigned short* Wth = (unsigned short*)ws; ws += (size_t)2 * HD * NFE * sizeof(short);
    unsigned short* Wtl = (unsigned short*)ws; ws += (size_t)2 * HD * NFE * sizeof(short);

    hipMemsetAsync(deg, 0, N_NODES * sizeof(int), stream);
    count_deg<<<(ET + 255) / 256, 256, 0, stream>>>(ei, deg);
    scan_offsets<<<1, 1024, 0, stream>>>(deg, offs, cursor);
    fill_csr<<<(ET + 255) / 256, 256, 0, stream>>>(ei, cursor, esrc);

    split_x<<<(N_NODES * NFE / 4 + 255) / 256, 256, 0, stream>>>(x, xh, xlo);
    split_w<<<dim3((NFE * HD + 255) / 256, 2), 256, 0, stream>>>(W_l1, W_r1, Wth, Wtl);

    gemm1m<<<G1_NWG, 256, 0, stream>>>(xh, xlo, Wth, Wtl, b_l1, b_r1, xl1, xr1);
    fused1<<<(N_NODES + 3) / 4, 256, 0, stream>>>(offs, esrc, xl1, xr1, att1, bias1, hbuf);

    gemm2<<<(N_NODES + 7) / 8, 256, 0, stream>>>(hbuf, W_l2, b_l2, W_r2, b_r2, xl2, xr2);
    fused2<<<(N_NODES + 3) / 4, 256, 0, stream>>>(offs, esrc, xl2, xr2, att2, bias2, out);
}